// Round 2
// baseline (1947.262 us; speedup 1.0000x reference)
//
#include <hip/hip_runtime.h>
#include <cstdint>
#include <cstddef>

// Problem constants (from reference setup_inputs)
#define N_NODES 50000
#define FDIM    256
#define HDIM    64
#define E_EDGES 1600000
#define BATCH_N 1000000

// ---------------------------------------------------------------------------
// K1: x1 = feat @ W  (N x 256) @ (256 x 64) -> fp32, plus attention scalars
//     ssrc[n] = x1[n,:] . a[:64],  sdst[n] = x1[n,:] . a[64:]
// One wave per node; lane = output channel. Feat row distributed via shfl.
// ---------------------------------------------------------------------------
__global__ void feat_gemm_attn(const float* __restrict__ feat,
                               const float* __restrict__ W,
                               const float* __restrict__ a,
                               float* __restrict__ x1,
                               float* __restrict__ ssrc,
                               float* __restrict__ sdst,
                               int n_nodes) {
  int wid  = (blockIdx.x * blockDim.x + threadIdx.x) >> 6;
  int lane = threadIdx.x & 63;
  if (wid >= n_nodes) return;
  const float* fr = feat + (size_t)wid * FDIM;
  // lane holds feat elements [4*lane .. 4*lane+3]
  float4 v = ((const float4*)fr)[lane];
  float acc = 0.f;
#pragma unroll 8
  for (int j = 0; j < 64; ++j) {
    float a0 = __shfl(v.x, j);
    float a1 = __shfl(v.y, j);
    float a2 = __shfl(v.z, j);
    float a3 = __shfl(v.w, j);
    const float* wp = W + (j * 4) * HDIM + lane;
    acc = fmaf(a0, wp[0 * HDIM], acc);
    acc = fmaf(a1, wp[1 * HDIM], acc);
    acc = fmaf(a2, wp[2 * HDIM], acc);
    acc = fmaf(a3, wp[3 * HDIM], acc);
  }
  x1[(size_t)wid * HDIM + lane] = acc;
  float ps = acc * a[lane];
  float pd = acc * a[HDIM + lane];
#pragma unroll
  for (int d = 32; d > 0; d >>= 1) {
    ps += __shfl_xor(ps, d);
    pd += __shfl_xor(pd, d);
  }
  if (lane == 0) { ssrc[wid] = ps; sdst[wid] = pd; }
}

// ---------------------------------------------------------------------------
// K2: per-edge out-degree histogram on src
// ---------------------------------------------------------------------------
__global__ void edge_count(const int2* __restrict__ edges,
                           int* __restrict__ cnt, int n_edges) {
  int e = blockIdx.x * blockDim.x + threadIdx.x;
  if (e >= n_edges) return;
  atomicAdd(&cnt[edges[e].x], 1);
}

// ---------------------------------------------------------------------------
// K3: single-block exclusive scan (in place: counts -> offsets), cur = copy
// ---------------------------------------------------------------------------
__global__ void scan_kernel(int* __restrict__ off, int* __restrict__ cur, int n) {
  const int T = 1024;
  __shared__ int sh[T];
  int tid   = threadIdx.x;
  int chunk = (n + T - 1) / T;
  int beg   = tid * chunk;
  int end   = beg + chunk;
  if (end > n) end = n;
  if (beg > n) beg = n;
  int s = 0;
  for (int i = beg; i < end; ++i) s += off[i];
  sh[tid] = s;
  __syncthreads();
#pragma unroll
  for (int d = 1; d < T; d <<= 1) {
    int t = (tid >= d) ? sh[tid - d] : 0;
    __syncthreads();
    sh[tid] += t;
    __syncthreads();
  }
  int total = sh[T - 1];
  int run   = sh[tid] - s;  // exclusive prefix of this thread's chunk
  for (int i = beg; i < end; ++i) {
    int v = off[i];
    off[i] = run;
    cur[i] = run;
    run += v;
  }
  if (tid == 0) off[n] = total;
}

// ---------------------------------------------------------------------------
// K4: per-edge attention weight + CSR scatter of (w, dst) by src
// scores = leaky_relu(ssrc[src]+sdst[dst], 0.2) (+ graph_w[type]); w = sigmoid
// ---------------------------------------------------------------------------
__global__ void edge_w_scatter(const int2* __restrict__ edges,
                               const int* __restrict__ etype,     // nullable
                               const float* __restrict__ gw,      // nullable
                               const float* __restrict__ ssrc,
                               const float* __restrict__ sdst,
                               int* __restrict__ cur,
                               float* __restrict__ wbuf,
                               int* __restrict__ dbuf,
                               int n_edges) {
  int e = blockIdx.x * blockDim.x + threadIdx.x;
  if (e >= n_edges) return;
  int2 ed = edges[e];
  float x = ssrc[ed.x] + sdst[ed.y];
  x = (x >= 0.f) ? x : 0.2f * x;
  if (etype) x += gw[etype[e]];
  float w = 1.f / (1.f + __expf(-x));
  int pos = atomicAdd(&cur[ed.x], 1);
  wbuf[pos] = w;
  dbuf[pos] = ed.y;
}

// ---------------------------------------------------------------------------
// K5: gather aggregation, one wave per node (no float atomics).
// x2[n] = (sum_e w_e * x1[dst_e]) / max(sum_e w_e, 1e-8)
// ---------------------------------------------------------------------------
__global__ void aggregate(const int* __restrict__ off,
                          const float* __restrict__ wbuf,
                          const int* __restrict__ dbuf,
                          const float* __restrict__ x1,
                          float* __restrict__ x2,
                          int n_nodes) {
  int wid  = (blockIdx.x * blockDim.x + threadIdx.x) >> 6;
  int lane = threadIdx.x & 63;
  if (wid >= n_nodes) return;
  int beg = off[wid], end = off[wid + 1];
  float acc = 0.f, wsum = 0.f;
  for (int j = beg; j < end; ++j) {
    float w = wbuf[j];
    int   d = dbuf[j];
    wsum += w;
    acc = fmaf(w, x1[(size_t)d * HDIM + lane], acc);
  }
  x2[(size_t)wid * HDIM + lane] = acc / fmaxf(wsum, 1e-8f);
}

// ---------------------------------------------------------------------------
// K6: x3 = relu(x2@Wg + bg + feat@Ws + bs); emb = relu(x3@Wo + bo) + base
// One wave per node. Writes fp32 emb directly into d_out region.
// ---------------------------------------------------------------------------
__global__ void node_emb(const float* __restrict__ x2,
                         const float* __restrict__ feat,
                         const float* __restrict__ Wg,
                         const float* __restrict__ bg,
                         const float* __restrict__ Ws,
                         const float* __restrict__ bs,
                         const float* __restrict__ Wo,
                         const float* __restrict__ bo,
                         const float* __restrict__ base,
                         float* __restrict__ emb,
                         int n_nodes) {
  int wid  = (blockIdx.x * blockDim.x + threadIdx.x) >> 6;
  int lane = threadIdx.x & 63;
  if (wid >= n_nodes) return;
  float u2v = x2[(size_t)wid * HDIM + lane];
  float acc = bg[lane] + bs[lane];
#pragma unroll 8
  for (int k = 0; k < 64; ++k)
    acc = fmaf(__shfl(u2v, k), Wg[k * HDIM + lane], acc);
  const float* fr = feat + (size_t)wid * FDIM;
  float4 v = ((const float4*)fr)[lane];
#pragma unroll 8
  for (int j = 0; j < 64; ++j) {
    float a0 = __shfl(v.x, j);
    float a1 = __shfl(v.y, j);
    float a2 = __shfl(v.z, j);
    float a3 = __shfl(v.w, j);
    const float* wp = Ws + (j * 4) * HDIM + lane;
    acc = fmaf(a0, wp[0 * HDIM], acc);
    acc = fmaf(a1, wp[1 * HDIM], acc);
    acc = fmaf(a2, wp[2 * HDIM], acc);
    acc = fmaf(a3, wp[3 * HDIM], acc);
  }
  float u3 = fmaxf(acc, 0.f);
  float acc2 = bo[lane];
#pragma unroll 8
  for (int k = 0; k < 64; ++k)
    acc2 = fmaf(__shfl(u3, k), Wo[k * HDIM + lane], acc2);
  float e = fmaxf(acc2, 0.f) + base[(size_t)wid * HDIM + lane];
  emb[(size_t)wid * HDIM + lane] = e;
}

// ---------------------------------------------------------------------------
// K7: scoring — one wave per (user, business) pair
// ---------------------------------------------------------------------------
__global__ void score_kernel(const int* __restrict__ uidx,
                             const int* __restrict__ bidx,
                             const float* __restrict__ uemb,
                             const float* __restrict__ bemb,
                             const float* __restrict__ ubias,
                             const float* __restrict__ bbias,
                             const float* __restrict__ gbias,
                             float* __restrict__ pred,
                             int batch) {
  int wid  = (blockIdx.x * blockDim.x + threadIdx.x) >> 6;
  int lane = threadIdx.x & 63;
  if (wid >= batch) return;
  int u = uidx[wid], b = bidx[wid];
  float p = uemb[(size_t)u * HDIM + lane] * bemb[(size_t)b * HDIM + lane];
#pragma unroll
  for (int d = 32; d > 0; d >>= 1) p += __shfl_xor(p, d);
  if (lane == 0) {
    float s  = p + ubias[u] + bbias[b] + gbias[0];
    pred[wid] = 4.f / (1.f + __expf(-s)) + 1.f;
  }
}

// ---------------------------------------------------------------------------
extern "C" void kernel_launch(void* const* d_in, const int* in_sizes, int n_in,
                              void* d_out, int out_size, void* d_ws, size_t ws_size,
                              hipStream_t stream) {
  const float* uf    = (const float*)d_in[0];
  const float* bfeat = (const float*)d_in[1];
  const int*   ue    = (const int*)d_in[2];
  const int*   be    = (const int*)d_in[3];
  const int*   bet   = (const int*)d_in[4];
  const int*   uidx  = (const int*)d_in[5];
  const int*   bidx  = (const int*)d_in[6];
  const float* Wu    = (const float*)d_in[7];
  const float* Wb    = (const float*)d_in[8];
  const float* au    = (const float*)d_in[9];
  const float* ab    = (const float*)d_in[10];
  const float* gw    = (const float*)d_in[11];
  const float* Wug   = (const float*)d_in[12];
  const float* bug   = (const float*)d_in[13];
  const float* Wus   = (const float*)d_in[14];
  const float* bus   = (const float*)d_in[15];
  const float* Wbg   = (const float*)d_in[16];
  const float* bbg   = (const float*)d_in[17];
  const float* Wbs   = (const float*)d_in[18];
  const float* bbs   = (const float*)d_in[19];
  const float* Wuo   = (const float*)d_in[20];
  const float* buo   = (const float*)d_in[21];
  const float* Wbo   = (const float*)d_in[22];
  const float* bbo   = (const float*)d_in[23];
  const float* ubase = (const float*)d_in[24];
  const float* bbase = (const float*)d_in[25];
  const float* ubias = (const float*)d_in[26];
  const float* bbias = (const float*)d_in[27];
  const float* gbias = (const float*)d_in[28];

  // Workspace layout (4-byte units)
  float* W4 = (float*)d_ws;
  const size_t NH = (size_t)N_NODES * HDIM;  // 3,200,000
  float* u1     = W4;                        // x1 user
  float* b1     = W4 + NH;                   // x1 business
  float* u2     = W4 + 2 * NH;
  float* b2     = W4 + 3 * NH;
  float* ssrc_u = W4 + 4 * NH;
  float* sdst_u = ssrc_u + N_NODES;
  float* ssrc_b = sdst_u + N_NODES;
  float* sdst_b = ssrc_b + N_NODES;
  int*   off_u  = (int*)(sdst_b + N_NODES);  // N+1
  int*   cur_u  = off_u + (N_NODES + 1);
  int*   off_b  = cur_u + N_NODES;           // N+1
  int*   cur_b  = off_b + (N_NODES + 1);
  float* wbuf_u = (float*)(cur_b + N_NODES);
  int*   dbuf_u = (int*)(wbuf_u + E_EDGES);
  float* wbuf_b = (float*)(dbuf_u + E_EDGES);
  int*   dbuf_b = (int*)(wbuf_b + E_EDGES);

  float* out      = (float*)d_out;
  float* out_pred = out;                     // BATCH_N
  float* out_uemb = out + BATCH_N;           // NH
  float* out_bemb = out + BATCH_N + NH;      // NH

  const int BLK = 256;
  const int node_blocks = (N_NODES * 64 + BLK - 1) / BLK;   // wave per node
  const int edge_blocks = (E_EDGES + BLK - 1) / BLK;
  const int pair_blocks = (BATCH_N * 64 + BLK - 1) / BLK;   // wave per pair

  // zero the degree-count arrays (ws is poisoned 0xAA before each call)
  hipMemsetAsync(off_u, 0, (N_NODES + 1) * sizeof(int), stream);
  hipMemsetAsync(off_b, 0, (N_NODES + 1) * sizeof(int), stream);

  feat_gemm_attn<<<node_blocks, BLK, 0, stream>>>(uf, Wu, au, u1, ssrc_u, sdst_u, N_NODES);
  feat_gemm_attn<<<node_blocks, BLK, 0, stream>>>(bfeat, Wb, ab, b1, ssrc_b, sdst_b, N_NODES);

  edge_count<<<edge_blocks, BLK, 0, stream>>>((const int2*)ue, off_u, E_EDGES);
  edge_count<<<edge_blocks, BLK, 0, stream>>>((const int2*)be, off_b, E_EDGES);

  scan_kernel<<<1, 1024, 0, stream>>>(off_u, cur_u, N_NODES);
  scan_kernel<<<1, 1024, 0, stream>>>(off_b, cur_b, N_NODES);

  edge_w_scatter<<<edge_blocks, BLK, 0, stream>>>((const int2*)ue, nullptr, nullptr,
                                                  ssrc_u, sdst_u, cur_u, wbuf_u, dbuf_u, E_EDGES);
  edge_w_scatter<<<edge_blocks, BLK, 0, stream>>>((const int2*)be, bet, gw,
                                                  ssrc_b, sdst_b, cur_b, wbuf_b, dbuf_b, E_EDGES);

  aggregate<<<node_blocks, BLK, 0, stream>>>(off_u, wbuf_u, dbuf_u, u1, u2, N_NODES);
  aggregate<<<node_blocks, BLK, 0, stream>>>(off_b, wbuf_b, dbuf_b, b1, b2, N_NODES);

  node_emb<<<node_blocks, BLK, 0, stream>>>(u2, uf, Wug, bug, Wus, bus, Wuo, buo,
                                            ubase, out_uemb, N_NODES);
  node_emb<<<node_blocks, BLK, 0, stream>>>(b2, bfeat, Wbg, bbg, Wbs, bbs, Wbo, bbo,
                                            bbase, out_bemb, N_NODES);

  score_kernel<<<pair_blocks, BLK, 0, stream>>>(uidx, bidx, out_uemb, out_bemb,
                                                ubias, bbias, gbias, out_pred, BATCH_N);
}

// Round 3
// 1432.588 us; speedup vs baseline: 1.3593x; 1.3593x over previous
//
#include <hip/hip_runtime.h>
#include <cstdint>
#include <cstddef>

// Problem constants (from reference setup_inputs)
#define N_NODES 50000
#define FDIM    256
#define HDIM    64
#define E_EDGES 1600000
#define BATCH_N 1000000

// ---------------------------------------------------------------------------
// K1: tiled fp32 GEMM  C[M x 64] = A[M x 256] @ B[256 x 64]
// Optional fused attention scalars: ssrc[m] = C[m,:].a[:64], sdst = C[m,:].a[64:]
// Block: 256 threads, 64-row tile, 4x4 micro-tile/thread, K chunked by 64.
// As staged transposed [k][m] with pad 68 (16B-aligned rows, bank-rotated).
// ---------------------------------------------------------------------------
__global__ __launch_bounds__(256) void gemm_k256(const float* __restrict__ A,
                                                 const float* __restrict__ B,
                                                 float* __restrict__ C, int M,
                                                 const float* __restrict__ a_att,
                                                 float* __restrict__ ssrc,
                                                 float* __restrict__ sdst) {
  __shared__ float As[64][68];
  __shared__ float Bs[64][64];
  const int t  = threadIdx.x;
  const int tx = t & 15;        // N direction (cols tx*4..+3)
  const int ty = t >> 4;        // M direction (rows ty*4..+3)
  const int m0 = blockIdx.x * 64;

  float acc[4][4] = {};

  for (int kc = 0; kc < 4; ++kc) {
    __syncthreads();
#pragma unroll
    for (int i = 0; i < 4; ++i) {
      int f = t + i * 256;            // 0..1023
      int row = f >> 4, c4 = f & 15;  // row in tile, float4-col in chunk
      int mg = m0 + row; mg = (mg < M) ? mg : (M - 1);
      float4 va = *(const float4*)(A + (size_t)mg * FDIM + kc * 64 + c4 * 4);
      As[c4 * 4 + 0][row] = va.x;
      As[c4 * 4 + 1][row] = va.y;
      As[c4 * 4 + 2][row] = va.z;
      As[c4 * 4 + 3][row] = va.w;
      *(float4*)(&Bs[row][c4 * 4]) =
          *(const float4*)(B + (size_t)(kc * 64 + row) * HDIM + c4 * 4);
    }
    __syncthreads();
#pragma unroll 4
    for (int k = 0; k < 64; ++k) {
      float4 a = *(const float4*)(&As[k][ty * 4]);
      float4 b = *(const float4*)(&Bs[k][tx * 4]);
      acc[0][0] = fmaf(a.x, b.x, acc[0][0]);
      acc[0][1] = fmaf(a.x, b.y, acc[0][1]);
      acc[0][2] = fmaf(a.x, b.z, acc[0][2]);
      acc[0][3] = fmaf(a.x, b.w, acc[0][3]);
      acc[1][0] = fmaf(a.y, b.x, acc[1][0]);
      acc[1][1] = fmaf(a.y, b.y, acc[1][1]);
      acc[1][2] = fmaf(a.y, b.z, acc[1][2]);
      acc[1][3] = fmaf(a.y, b.w, acc[1][3]);
      acc[2][0] = fmaf(a.z, b.x, acc[2][0]);
      acc[2][1] = fmaf(a.z, b.y, acc[2][1]);
      acc[2][2] = fmaf(a.z, b.z, acc[2][2]);
      acc[2][3] = fmaf(a.z, b.w, acc[2][3]);
      acc[3][0] = fmaf(a.w, b.x, acc[3][0]);
      acc[3][1] = fmaf(a.w, b.y, acc[3][1]);
      acc[3][2] = fmaf(a.w, b.z, acc[3][2]);
      acc[3][3] = fmaf(a.w, b.w, acc[3][3]);
    }
  }

#pragma unroll
  for (int i = 0; i < 4; ++i) {
    int m = m0 + ty * 4 + i;
    if (m < M)
      *(float4*)(C + (size_t)m * HDIM + tx * 4) =
          make_float4(acc[i][0], acc[i][1], acc[i][2], acc[i][3]);
  }

  if (a_att) {
    float4 aa1 = *(const float4*)(a_att + tx * 4);
    float4 aa2 = *(const float4*)(a_att + HDIM + tx * 4);
#pragma unroll
    for (int i = 0; i < 4; ++i) {
      float s1 = acc[i][0] * aa1.x + acc[i][1] * aa1.y +
                 acc[i][2] * aa1.z + acc[i][3] * aa1.w;
      float s2 = acc[i][0] * aa2.x + acc[i][1] * aa2.y +
                 acc[i][2] * aa2.z + acc[i][3] * aa2.w;
#pragma unroll
      for (int d = 1; d < 16; d <<= 1) {
        s1 += __shfl_xor(s1, d);
        s2 += __shfl_xor(s2, d);
      }
      int m = m0 + ty * 4 + i;
      if (tx == 0 && m < M) { ssrc[m] = s1; sdst[m] = s2; }
    }
  }
}

// ---------------------------------------------------------------------------
// K2: per-edge out-degree histogram on src
// ---------------------------------------------------------------------------
__global__ void edge_count(const int2* __restrict__ edges,
                           int* __restrict__ cnt, int n_edges) {
  int e = blockIdx.x * blockDim.x + threadIdx.x;
  if (e >= n_edges) return;
  atomicAdd(&cnt[edges[e].x], 1);
}

// ---------------------------------------------------------------------------
// K3: single-block exclusive scan (in place: counts -> offsets), cur = copy
// ---------------------------------------------------------------------------
__global__ void scan_kernel(int* __restrict__ off, int* __restrict__ cur, int n) {
  const int T = 1024;
  __shared__ int sh[T];
  int tid   = threadIdx.x;
  int chunk = (n + T - 1) / T;
  int beg   = tid * chunk;
  int end   = beg + chunk;
  if (end > n) end = n;
  if (beg > n) beg = n;
  int s = 0;
  for (int i = beg; i < end; ++i) s += off[i];
  sh[tid] = s;
  __syncthreads();
#pragma unroll
  for (int d = 1; d < T; d <<= 1) {
    int t = (tid >= d) ? sh[tid - d] : 0;
    __syncthreads();
    sh[tid] += t;
    __syncthreads();
  }
  int total = sh[T - 1];
  int run   = sh[tid] - s;  // exclusive prefix of this thread's chunk
  for (int i = beg; i < end; ++i) {
    int v = off[i];
    off[i] = run;
    cur[i] = run;
    run += v;
  }
  if (tid == 0) off[n] = total;
}

// ---------------------------------------------------------------------------
// K4: per-edge attention weight + CSR scatter of (w, dst) by src
// ---------------------------------------------------------------------------
__global__ void edge_w_scatter(const int2* __restrict__ edges,
                               const int* __restrict__ etype,     // nullable
                               const float* __restrict__ gw,      // nullable
                               const float* __restrict__ ssrc,
                               const float* __restrict__ sdst,
                               int* __restrict__ cur,
                               float* __restrict__ wbuf,
                               int* __restrict__ dbuf,
                               int n_edges) {
  int e = blockIdx.x * blockDim.x + threadIdx.x;
  if (e >= n_edges) return;
  int2 ed = edges[e];
  float x = ssrc[ed.x] + sdst[ed.y];
  x = (x >= 0.f) ? x : 0.2f * x;
  if (etype) x += gw[etype[e]];
  float w = 1.f / (1.f + __expf(-x));
  int pos = atomicAdd(&cur[ed.x], 1);
  wbuf[pos] = w;
  dbuf[pos] = ed.y;
}

// ---------------------------------------------------------------------------
// K5: gather aggregation, one wave per node (no float atomics).
// x2[n] = (sum_e w_e * x1[dst_e]) / max(sum_e w_e, 1e-8)
// ---------------------------------------------------------------------------
__global__ void aggregate(const int* __restrict__ off,
                          const float* __restrict__ wbuf,
                          const int* __restrict__ dbuf,
                          const float* __restrict__ x1,
                          float* __restrict__ x2,
                          int n_nodes) {
  int wid  = (blockIdx.x * blockDim.x + threadIdx.x) >> 6;
  int lane = threadIdx.x & 63;
  if (wid >= n_nodes) return;
  int beg = off[wid], end = off[wid + 1];
  float acc = 0.f, wsum = 0.f;
  for (int j = beg; j < end; ++j) {
    float w = wbuf[j];
    int   d = dbuf[j];
    wsum += w;
    acc = fmaf(w, x1[(size_t)d * HDIM + lane], acc);
  }
  x2[(size_t)wid * HDIM + lane] = acc / fmaxf(wsum, 1e-8f);
}

// ---------------------------------------------------------------------------
// K6: fused output head (per 64-node tile):
//   u3  = relu(x2@Wg + bg + t + bs)      (t = feat@Ws, precomputed)
//   emb = relu(u3@Wo + bo) + base
// ---------------------------------------------------------------------------
__global__ __launch_bounds__(256) void emb_kernel(const float* __restrict__ x2,
                                                  const float* __restrict__ tadd,
                                                  const float* __restrict__ Wg,
                                                  const float* __restrict__ Wo,
                                                  const float* __restrict__ bg,
                                                  const float* __restrict__ bs,
                                                  const float* __restrict__ bo,
                                                  const float* __restrict__ base,
                                                  float* __restrict__ emb, int M) {
  __shared__ float Xs[64][68];   // x2 transposed [k][m]; reused as u3 [n][m]
  __shared__ float Wgs[64][64];
  __shared__ float Wos[64][64];
  const int t  = threadIdx.x;
  const int tx = t & 15;
  const int ty = t >> 4;
  const int m0 = blockIdx.x * 64;

#pragma unroll
  for (int i = 0; i < 4; ++i) {
    int f = t + i * 256;
    int row = f >> 4, c4 = f & 15;
    int mg = m0 + row; mg = (mg < M) ? mg : (M - 1);
    float4 v = *(const float4*)(x2 + (size_t)mg * HDIM + c4 * 4);
    Xs[c4 * 4 + 0][row] = v.x;
    Xs[c4 * 4 + 1][row] = v.y;
    Xs[c4 * 4 + 2][row] = v.z;
    Xs[c4 * 4 + 3][row] = v.w;
    *(float4*)(&Wgs[row][c4 * 4]) = *(const float4*)(Wg + (size_t)row * HDIM + c4 * 4);
    *(float4*)(&Wos[row][c4 * 4]) = *(const float4*)(Wo + (size_t)row * HDIM + c4 * 4);
  }

  // acc init = t + bg + bs
  float4 bgv = *(const float4*)(bg + tx * 4);
  float4 bsv = *(const float4*)(bs + tx * 4);
  float acc[4][4];
#pragma unroll
  for (int i = 0; i < 4; ++i) {
    int mg = m0 + ty * 4 + i; mg = (mg < M) ? mg : (M - 1);
    float4 tv = *(const float4*)(tadd + (size_t)mg * HDIM + tx * 4);
    acc[i][0] = tv.x + bgv.x + bsv.x;
    acc[i][1] = tv.y + bgv.y + bsv.y;
    acc[i][2] = tv.z + bgv.z + bsv.z;
    acc[i][3] = tv.w + bgv.w + bsv.w;
  }
  __syncthreads();

#pragma unroll 4
  for (int k = 0; k < 64; ++k) {
    float4 a = *(const float4*)(&Xs[k][ty * 4]);
    float4 b = *(const float4*)(&Wgs[k][tx * 4]);
    acc[0][0] = fmaf(a.x, b.x, acc[0][0]);
    acc[0][1] = fmaf(a.x, b.y, acc[0][1]);
    acc[0][2] = fmaf(a.x, b.z, acc[0][2]);
    acc[0][3] = fmaf(a.x, b.w, acc[0][3]);
    acc[1][0] = fmaf(a.y, b.x, acc[1][0]);
    acc[1][1] = fmaf(a.y, b.y, acc[1][1]);
    acc[1][2] = fmaf(a.y, b.z, acc[1][2]);
    acc[1][3] = fmaf(a.y, b.w, acc[1][3]);
    acc[2][0] = fmaf(a.z, b.x, acc[2][0]);
    acc[2][1] = fmaf(a.z, b.y, acc[2][1]);
    acc[2][2] = fmaf(a.z, b.z, acc[2][2]);
    acc[2][3] = fmaf(a.z, b.w, acc[2][3]);
    acc[3][0] = fmaf(a.w, b.x, acc[3][0]);
    acc[3][1] = fmaf(a.w, b.y, acc[3][1]);
    acc[3][2] = fmaf(a.w, b.z, acc[3][2]);
    acc[3][3] = fmaf(a.w, b.w, acc[3][3]);
  }
  __syncthreads();   // everyone done reading Xs (x2) before reuse

  // u3 = relu(acc) -> Xs as [n][m]
#pragma unroll
  for (int i = 0; i < 4; ++i)
#pragma unroll
    for (int j = 0; j < 4; ++j)
      Xs[tx * 4 + j][ty * 4 + i] = fmaxf(acc[i][j], 0.f);
  __syncthreads();

  float4 bov = *(const float4*)(bo + tx * 4);
  float acc2[4][4];
#pragma unroll
  for (int i = 0; i < 4; ++i) {
    acc2[i][0] = bov.x; acc2[i][1] = bov.y; acc2[i][2] = bov.z; acc2[i][3] = bov.w;
  }
#pragma unroll 4
  for (int k = 0; k < 64; ++k) {
    float4 a = *(const float4*)(&Xs[k][ty * 4]);
    float4 b = *(const float4*)(&Wos[k][tx * 4]);
    acc2[0][0] = fmaf(a.x, b.x, acc2[0][0]);
    acc2[0][1] = fmaf(a.x, b.y, acc2[0][1]);
    acc2[0][2] = fmaf(a.x, b.z, acc2[0][2]);
    acc2[0][3] = fmaf(a.x, b.w, acc2[0][3]);
    acc2[1][0] = fmaf(a.y, b.x, acc2[1][0]);
    acc2[1][1] = fmaf(a.y, b.y, acc2[1][1]);
    acc2[1][2] = fmaf(a.y, b.z, acc2[1][2]);
    acc2[1][3] = fmaf(a.y, b.w, acc2[1][3]);
    acc2[2][0] = fmaf(a.z, b.x, acc2[2][0]);
    acc2[2][1] = fmaf(a.z, b.y, acc2[2][1]);
    acc2[2][2] = fmaf(a.z, b.z, acc2[2][2]);
    acc2[2][3] = fmaf(a.z, b.w, acc2[2][3]);
    acc2[3][0] = fmaf(a.w, b.x, acc2[3][0]);
    acc2[3][1] = fmaf(a.w, b.y, acc2[3][1]);
    acc2[3][2] = fmaf(a.w, b.z, acc2[3][2]);
    acc2[3][3] = fmaf(a.w, b.w, acc2[3][3]);
  }

#pragma unroll
  for (int i = 0; i < 4; ++i) {
    int m = m0 + ty * 4 + i;
    if (m < M) {
      float4 bb = *(const float4*)(base + (size_t)m * HDIM + tx * 4);
      *(float4*)(emb + (size_t)m * HDIM + tx * 4) =
          make_float4(fmaxf(acc2[i][0], 0.f) + bb.x,
                      fmaxf(acc2[i][1], 0.f) + bb.y,
                      fmaxf(acc2[i][2], 0.f) + bb.z,
                      fmaxf(acc2[i][3], 0.f) + bb.w);
    }
  }
}

// ---------------------------------------------------------------------------
// K7: scoring — one wave per (user, business) pair
// ---------------------------------------------------------------------------
__global__ void score_kernel(const int* __restrict__ uidx,
                             const int* __restrict__ bidx,
                             const float* __restrict__ uemb,
                             const float* __restrict__ bemb,
                             const float* __restrict__ ubias,
                             const float* __restrict__ bbias,
                             const float* __restrict__ gbias,
                             float* __restrict__ pred,
                             int batch) {
  int wid  = (blockIdx.x * blockDim.x + threadIdx.x) >> 6;
  int lane = threadIdx.x & 63;
  if (wid >= batch) return;
  int u = uidx[wid], b = bidx[wid];
  float p = uemb[(size_t)u * HDIM + lane] * bemb[(size_t)b * HDIM + lane];
#pragma unroll
  for (int d = 32; d > 0; d >>= 1) p += __shfl_xor(p, d);
  if (lane == 0) {
    float s  = p + ubias[u] + bbias[b] + gbias[0];
    pred[wid] = 4.f / (1.f + __expf(-s)) + 1.f;
  }
}

// ---------------------------------------------------------------------------
extern "C" void kernel_launch(void* const* d_in, const int* in_sizes, int n_in,
                              void* d_out, int out_size, void* d_ws, size_t ws_size,
                              hipStream_t stream) {
  const float* uf    = (const float*)d_in[0];
  const float* bfeat = (const float*)d_in[1];
  const int*   ue    = (const int*)d_in[2];
  const int*   be    = (const int*)d_in[3];
  const int*   bet   = (const int*)d_in[4];
  const int*   uidx  = (const int*)d_in[5];
  const int*   bidx  = (const int*)d_in[6];
  const float* Wu    = (const float*)d_in[7];
  const float* Wb    = (const float*)d_in[8];
  const float* au    = (const float*)d_in[9];
  const float* ab    = (const float*)d_in[10];
  const float* gw    = (const float*)d_in[11];
  const float* Wug   = (const float*)d_in[12];
  const float* bug   = (const float*)d_in[13];
  const float* Wus   = (const float*)d_in[14];
  const float* bus   = (const float*)d_in[15];
  const float* Wbg   = (const float*)d_in[16];
  const float* bbg   = (const float*)d_in[17];
  const float* Wbs   = (const float*)d_in[18];
  const float* bbs   = (const float*)d_in[19];
  const float* Wuo   = (const float*)d_in[20];
  const float* buo   = (const float*)d_in[21];
  const float* Wbo   = (const float*)d_in[22];
  const float* bbo   = (const float*)d_in[23];
  const float* ubase = (const float*)d_in[24];
  const float* bbase = (const float*)d_in[25];
  const float* ubias = (const float*)d_in[26];
  const float* bbias = (const float*)d_in[27];
  const float* gbias = (const float*)d_in[28];

  // Workspace layout (4-byte units)
  float* W4 = (float*)d_ws;
  const size_t NH = (size_t)N_NODES * HDIM;  // 3,200,000
  float* u1     = W4;                        // x1 user; later t_u = uf@Wus
  float* b1     = W4 + NH;                   // x1 business; later t_b
  float* u2     = W4 + 2 * NH;
  float* b2     = W4 + 3 * NH;
  float* ssrc_u = W4 + 4 * NH;
  float* sdst_u = ssrc_u + N_NODES;
  float* ssrc_b = sdst_u + N_NODES;
  float* sdst_b = ssrc_b + N_NODES;
  int*   off_u  = (int*)(sdst_b + N_NODES);  // N+1
  int*   cur_u  = off_u + (N_NODES + 1);
  int*   off_b  = cur_u + N_NODES;           // N+1
  int*   cur_b  = off_b + (N_NODES + 1);
  float* wbuf_u = (float*)(cur_b + N_NODES);
  int*   dbuf_u = (int*)(wbuf_u + E_EDGES);
  float* wbuf_b = (float*)(dbuf_u + E_EDGES);
  int*   dbuf_b = (int*)(wbuf_b + E_EDGES);

  float* out      = (float*)d_out;
  float* out_pred = out;                     // BATCH_N
  float* out_uemb = out + BATCH_N;           // NH
  float* out_bemb = out + BATCH_N + NH;      // NH

  const int BLK = 256;
  const int tile_blocks = (N_NODES + 63) / 64;              // 782
  const int node_blocks = (N_NODES * 64 + BLK - 1) / BLK;   // wave per node
  const int edge_blocks = (E_EDGES + BLK - 1) / BLK;
  const int pair_blocks = (BATCH_N * 64 + BLK - 1) / BLK;   // wave per pair

  hipMemsetAsync(off_u, 0, (N_NODES + 1) * sizeof(int), stream);
  hipMemsetAsync(off_b, 0, (N_NODES + 1) * sizeof(int), stream);

  // x1 = feat@W + fused attention scalars
  gemm_k256<<<tile_blocks, BLK, 0, stream>>>(uf, Wu, u1, N_NODES, au, ssrc_u, sdst_u);
  gemm_k256<<<tile_blocks, BLK, 0, stream>>>(bfeat, Wb, b1, N_NODES, ab, ssrc_b, sdst_b);

  edge_count<<<edge_blocks, BLK, 0, stream>>>((const int2*)ue, off_u, E_EDGES);
  edge_count<<<edge_blocks, BLK, 0, stream>>>((const int2*)be, off_b, E_EDGES);

  scan_kernel<<<1, 1024, 0, stream>>>(off_u, cur_u, N_NODES);
  scan_kernel<<<1, 1024, 0, stream>>>(off_b, cur_b, N_NODES);

  edge_w_scatter<<<edge_blocks, BLK, 0, stream>>>((const int2*)ue, nullptr, nullptr,
                                                  ssrc_u, sdst_u, cur_u, wbuf_u, dbuf_u, E_EDGES);
  edge_w_scatter<<<edge_blocks, BLK, 0, stream>>>((const int2*)be, bet, gw,
                                                  ssrc_b, sdst_b, cur_b, wbuf_b, dbuf_b, E_EDGES);

  aggregate<<<node_blocks, BLK, 0, stream>>>(off_u, wbuf_u, dbuf_u, u1, u2, N_NODES);
  aggregate<<<node_blocks, BLK, 0, stream>>>(off_b, wbuf_b, dbuf_b, b1, b2, N_NODES);

  // t = feat@Ws, overwriting dead x1 buffers
  gemm_k256<<<tile_blocks, BLK, 0, stream>>>(uf, Wus, u1, N_NODES, nullptr, nullptr, nullptr);
  gemm_k256<<<tile_blocks, BLK, 0, stream>>>(bfeat, Wbs, b1, N_NODES, nullptr, nullptr, nullptr);

  emb_kernel<<<tile_blocks, BLK, 0, stream>>>(u2, u1, Wug, Wuo, bug, bus, buo,
                                              ubase, out_uemb, N_NODES);
  emb_kernel<<<tile_blocks, BLK, 0, stream>>>(b2, b1, Wbg, Wbo, bbg, bbs, bbo,
                                              bbase, out_bemb, N_NODES);

  score_kernel<<<pair_blocks, BLK, 0, stream>>>(uidx, bidx, out_uemb, out_bemb,
                                                ubias, bbias, gbias, out_pred, BATCH_N);
}

// Round 4
// 1076.036 us; speedup vs baseline: 1.8097x; 1.3314x over previous
//
#include <hip/hip_runtime.h>
#include <cstdint>
#include <cstddef>

// Problem constants (from reference setup_inputs)
#define N_NODES 50000
#define FDIM    256
#define HDIM    64
#define E_EDGES 1600000
#define BATCH_N 1000000

// ---------------------------------------------------------------------------
// K1: tiled fp32 GEMM  C[M x 64] = A[M x 256] @ B[256 x 64]
// Optional fused attention scalars: ssrc[m] = C[m,:].a[:64], sdst = C[m,:].a[64:]
// ---------------------------------------------------------------------------
__global__ __launch_bounds__(256) void gemm_k256(const float* __restrict__ A,
                                                 const float* __restrict__ B,
                                                 float* __restrict__ C, int M,
                                                 const float* __restrict__ a_att,
                                                 float* __restrict__ ssrc,
                                                 float* __restrict__ sdst) {
  __shared__ float As[64][68];
  __shared__ float Bs[64][64];
  const int t  = threadIdx.x;
  const int tx = t & 15;        // N direction (cols tx*4..+3)
  const int ty = t >> 4;        // M direction (rows ty*4..+3)
  const int m0 = blockIdx.x * 64;

  float acc[4][4] = {};

  for (int kc = 0; kc < 4; ++kc) {
    __syncthreads();
#pragma unroll
    for (int i = 0; i < 4; ++i) {
      int f = t + i * 256;            // 0..1023
      int row = f >> 4, c4 = f & 15;  // row in tile, float4-col in chunk
      int mg = m0 + row; mg = (mg < M) ? mg : (M - 1);
      float4 va = *(const float4*)(A + (size_t)mg * FDIM + kc * 64 + c4 * 4);
      As[c4 * 4 + 0][row] = va.x;
      As[c4 * 4 + 1][row] = va.y;
      As[c4 * 4 + 2][row] = va.z;
      As[c4 * 4 + 3][row] = va.w;
      *(float4*)(&Bs[row][c4 * 4]) =
          *(const float4*)(B + (size_t)(kc * 64 + row) * HDIM + c4 * 4);
    }
    __syncthreads();
#pragma unroll 4
    for (int k = 0; k < 64; ++k) {
      float4 a = *(const float4*)(&As[k][ty * 4]);
      float4 b = *(const float4*)(&Bs[k][tx * 4]);
      acc[0][0] = fmaf(a.x, b.x, acc[0][0]);
      acc[0][1] = fmaf(a.x, b.y, acc[0][1]);
      acc[0][2] = fmaf(a.x, b.z, acc[0][2]);
      acc[0][3] = fmaf(a.x, b.w, acc[0][3]);
      acc[1][0] = fmaf(a.y, b.x, acc[1][0]);
      acc[1][1] = fmaf(a.y, b.y, acc[1][1]);
      acc[1][2] = fmaf(a.y, b.z, acc[1][2]);
      acc[1][3] = fmaf(a.y, b.w, acc[1][3]);
      acc[2][0] = fmaf(a.z, b.x, acc[2][0]);
      acc[2][1] = fmaf(a.z, b.y, acc[2][1]);
      acc[2][2] = fmaf(a.z, b.z, acc[2][2]);
      acc[2][3] = fmaf(a.z, b.w, acc[2][3]);
      acc[3][0] = fmaf(a.w, b.x, acc[3][0]);
      acc[3][1] = fmaf(a.w, b.y, acc[3][1]);
      acc[3][2] = fmaf(a.w, b.z, acc[3][2]);
      acc[3][3] = fmaf(a.w, b.w, acc[3][3]);
    }
  }

#pragma unroll
  for (int i = 0; i < 4; ++i) {
    int m = m0 + ty * 4 + i;
    if (m < M)
      *(float4*)(C + (size_t)m * HDIM + tx * 4) =
          make_float4(acc[i][0], acc[i][1], acc[i][2], acc[i][3]);
  }

  if (a_att) {
    float4 aa1 = *(const float4*)(a_att + tx * 4);
    float4 aa2 = *(const float4*)(a_att + HDIM + tx * 4);
#pragma unroll
    for (int i = 0; i < 4; ++i) {
      float s1 = acc[i][0] * aa1.x + acc[i][1] * aa1.y +
                 acc[i][2] * aa1.z + acc[i][3] * aa1.w;
      float s2 = acc[i][0] * aa2.x + acc[i][1] * aa2.y +
                 acc[i][2] * aa2.z + acc[i][3] * aa2.w;
#pragma unroll
      for (int d = 1; d < 16; d <<= 1) {
        s1 += __shfl_xor(s1, d);
        s2 += __shfl_xor(s2, d);
      }
      int m = m0 + ty * 4 + i;
      if (tx == 0 && m < M) { ssrc[m] = s1; sdst[m] = s2; }
    }
  }
}

// ---------------------------------------------------------------------------
// K2: per-edge out-degree histogram on src
// ---------------------------------------------------------------------------
__global__ void edge_count(const int2* __restrict__ edges,
                           int* __restrict__ cnt, int n_edges) {
  int e = blockIdx.x * blockDim.x + threadIdx.x;
  if (e >= n_edges) return;
  atomicAdd(&cnt[edges[e].x], 1);
}

// ---------------------------------------------------------------------------
// K3: single-block exclusive scan (in place: counts -> offsets), cur = copy
// ---------------------------------------------------------------------------
__global__ void scan_kernel(int* __restrict__ off, int* __restrict__ cur, int n) {
  const int T = 1024;
  __shared__ int sh[T];
  int tid   = threadIdx.x;
  int chunk = (n + T - 1) / T;
  int beg   = tid * chunk;
  int end   = beg + chunk;
  if (end > n) end = n;
  if (beg > n) beg = n;
  int s = 0;
  for (int i = beg; i < end; ++i) s += off[i];
  sh[tid] = s;
  __syncthreads();
#pragma unroll
  for (int d = 1; d < T; d <<= 1) {
    int t = (tid >= d) ? sh[tid - d] : 0;
    __syncthreads();
    sh[tid] += t;
    __syncthreads();
  }
  int total = sh[T - 1];
  int run   = sh[tid] - s;  // exclusive prefix of this thread's chunk
  for (int i = beg; i < end; ++i) {
    int v = off[i];
    off[i] = run;
    cur[i] = run;
    run += v;
  }
  if (tid == 0) off[n] = total;
}

// ---------------------------------------------------------------------------
// K4: per-edge attention weight + CSR scatter of (w, dst) fused 8B records
// ---------------------------------------------------------------------------
__global__ void edge_w_scatter(const int2* __restrict__ edges,
                               const int* __restrict__ etype,     // nullable
                               const float* __restrict__ gw,      // nullable
                               const float* __restrict__ ssrc,
                               const float* __restrict__ sdst,
                               int* __restrict__ cur,
                               float2* __restrict__ wdbuf,
                               int n_edges) {
  int e = blockIdx.x * blockDim.x + threadIdx.x;
  if (e >= n_edges) return;
  int2 ed = edges[e];
  float x = ssrc[ed.x] + sdst[ed.y];
  x = (x >= 0.f) ? x : 0.2f * x;
  if (etype) x += gw[etype[e]];
  float w = 1.f / (1.f + __expf(-x));
  int pos = atomicAdd(&cur[ed.x], 1);
  wdbuf[pos] = make_float2(w, __int_as_float(ed.y));
}

// ---------------------------------------------------------------------------
// K5: gather aggregation, one wave per node, 4 edges in flight,
// float4 row slices (16 lanes per row). No float atomics.
// x2[n] = (sum_e w_e * x1[dst_e]) / max(sum_e w_e, 1e-8)
// ---------------------------------------------------------------------------
__global__ void aggregate(const int* __restrict__ off,
                          const float2* __restrict__ wdbuf,
                          const float* __restrict__ x1,
                          float* __restrict__ x2,
                          int n_nodes) {
  int wid  = (blockIdx.x * blockDim.x + threadIdx.x) >> 6;
  int lane = threadIdx.x & 63;
  if (wid >= n_nodes) return;
  const int q  = lane & 15;   // float4 slice of the 64-wide row
  const int es = lane >> 4;   // edge slot 0..3
  int beg = off[wid], end = off[wid + 1];
  float4 acc = make_float4(0.f, 0.f, 0.f, 0.f);
  float wsum = 0.f;
  const float4* x1v = (const float4*)x1;
  for (int j = beg; j < end; j += 4) {
    int jj = j + es;
    bool valid = jj < end;
    float2 wd = wdbuf[valid ? jj : beg];   // beg always < end here
    float  w  = valid ? wd.x : 0.f;
    int    d  = __float_as_int(wd.y);
    float4 v  = x1v[(size_t)d * 16 + q];
    acc.x = fmaf(w, v.x, acc.x);
    acc.y = fmaf(w, v.y, acc.y);
    acc.z = fmaf(w, v.z, acc.z);
    acc.w = fmaf(w, v.w, acc.w);
    wsum += w;
  }
  // reduce across the 4 edge slots (xor 16, 32)
#pragma unroll
  for (int d = 16; d < 64; d <<= 1) {
    acc.x += __shfl_xor(acc.x, d);
    acc.y += __shfl_xor(acc.y, d);
    acc.z += __shfl_xor(acc.z, d);
    acc.w += __shfl_xor(acc.w, d);
    wsum  += __shfl_xor(wsum, d);
  }
  if (es == 0) {
    float inv = 1.f / fmaxf(wsum, 1e-8f);
    ((float4*)x2)[(size_t)wid * 16 + q] =
        make_float4(acc.x * inv, acc.y * inv, acc.z * inv, acc.w * inv);
  }
}

// ---------------------------------------------------------------------------
// K6: fused output head (per 64-node tile):
//   u3  = relu(x2@Wg + bg + t + bs)      (t = feat@Ws, precomputed)
//   emb = relu(u3@Wo + bo) + base
// ---------------------------------------------------------------------------
__global__ __launch_bounds__(256) void emb_kernel(const float* __restrict__ x2,
                                                  const float* __restrict__ tadd,
                                                  const float* __restrict__ Wg,
                                                  const float* __restrict__ Wo,
                                                  const float* __restrict__ bg,
                                                  const float* __restrict__ bs,
                                                  const float* __restrict__ bo,
                                                  const float* __restrict__ base,
                                                  float* __restrict__ emb, int M) {
  __shared__ float Xs[64][68];   // x2 transposed [k][m]; reused as u3 [n][m]
  __shared__ float Wgs[64][64];
  __shared__ float Wos[64][64];
  const int t  = threadIdx.x;
  const int tx = t & 15;
  const int ty = t >> 4;
  const int m0 = blockIdx.x * 64;

#pragma unroll
  for (int i = 0; i < 4; ++i) {
    int f = t + i * 256;
    int row = f >> 4, c4 = f & 15;
    int mg = m0 + row; mg = (mg < M) ? mg : (M - 1);
    float4 v = *(const float4*)(x2 + (size_t)mg * HDIM + c4 * 4);
    Xs[c4 * 4 + 0][row] = v.x;
    Xs[c4 * 4 + 1][row] = v.y;
    Xs[c4 * 4 + 2][row] = v.z;
    Xs[c4 * 4 + 3][row] = v.w;
    *(float4*)(&Wgs[row][c4 * 4]) = *(const float4*)(Wg + (size_t)row * HDIM + c4 * 4);
    *(float4*)(&Wos[row][c4 * 4]) = *(const float4*)(Wo + (size_t)row * HDIM + c4 * 4);
  }

  float4 bgv = *(const float4*)(bg + tx * 4);
  float4 bsv = *(const float4*)(bs + tx * 4);
  float acc[4][4];
#pragma unroll
  for (int i = 0; i < 4; ++i) {
    int mg = m0 + ty * 4 + i; mg = (mg < M) ? mg : (M - 1);
    float4 tv = *(const float4*)(tadd + (size_t)mg * HDIM + tx * 4);
    acc[i][0] = tv.x + bgv.x + bsv.x;
    acc[i][1] = tv.y + bgv.y + bsv.y;
    acc[i][2] = tv.z + bgv.z + bsv.z;
    acc[i][3] = tv.w + bgv.w + bsv.w;
  }
  __syncthreads();

#pragma unroll 4
  for (int k = 0; k < 64; ++k) {
    float4 a = *(const float4*)(&Xs[k][ty * 4]);
    float4 b = *(const float4*)(&Wgs[k][tx * 4]);
    acc[0][0] = fmaf(a.x, b.x, acc[0][0]);
    acc[0][1] = fmaf(a.x, b.y, acc[0][1]);
    acc[0][2] = fmaf(a.x, b.z, acc[0][2]);
    acc[0][3] = fmaf(a.x, b.w, acc[0][3]);
    acc[1][0] = fmaf(a.y, b.x, acc[1][0]);
    acc[1][1] = fmaf(a.y, b.y, acc[1][1]);
    acc[1][2] = fmaf(a.y, b.z, acc[1][2]);
    acc[1][3] = fmaf(a.y, b.w, acc[1][3]);
    acc[2][0] = fmaf(a.z, b.x, acc[2][0]);
    acc[2][1] = fmaf(a.z, b.y, acc[2][1]);
    acc[2][2] = fmaf(a.z, b.z, acc[2][2]);
    acc[2][3] = fmaf(a.z, b.w, acc[2][3]);
    acc[3][0] = fmaf(a.w, b.x, acc[3][0]);
    acc[3][1] = fmaf(a.w, b.y, acc[3][1]);
    acc[3][2] = fmaf(a.w, b.z, acc[3][2]);
    acc[3][3] = fmaf(a.w, b.w, acc[3][3]);
  }
  __syncthreads();

#pragma unroll
  for (int i = 0; i < 4; ++i)
#pragma unroll
    for (int j = 0; j < 4; ++j)
      Xs[tx * 4 + j][ty * 4 + i] = fmaxf(acc[i][j], 0.f);
  __syncthreads();

  float4 bov = *(const float4*)(bo + tx * 4);
  float acc2[4][4];
#pragma unroll
  for (int i = 0; i < 4; ++i) {
    acc2[i][0] = bov.x; acc2[i][1] = bov.y; acc2[i][2] = bov.z; acc2[i][3] = bov.w;
  }
#pragma unroll 4
  for (int k = 0; k < 64; ++k) {
    float4 a = *(const float4*)(&Xs[k][ty * 4]);
    float4 b = *(const float4*)(&Wos[k][tx * 4]);
    acc2[0][0] = fmaf(a.x, b.x, acc2[0][0]);
    acc2[0][1] = fmaf(a.x, b.y, acc2[0][1]);
    acc2[0][2] = fmaf(a.x, b.z, acc2[0][2]);
    acc2[0][3] = fmaf(a.x, b.w, acc2[0][3]);
    acc2[1][0] = fmaf(a.y, b.x, acc2[1][0]);
    acc2[1][1] = fmaf(a.y, b.y, acc2[1][1]);
    acc2[1][2] = fmaf(a.y, b.z, acc2[1][2]);
    acc2[1][3] = fmaf(a.y, b.w, acc2[1][3]);
    acc2[2][0] = fmaf(a.z, b.x, acc2[2][0]);
    acc2[2][1] = fmaf(a.z, b.y, acc2[2][1]);
    acc2[2][2] = fmaf(a.z, b.z, acc2[2][2]);
    acc2[2][3] = fmaf(a.z, b.w, acc2[2][3]);
    acc2[3][0] = fmaf(a.w, b.x, acc2[3][0]);
    acc2[3][1] = fmaf(a.w, b.y, acc2[3][1]);
    acc2[3][2] = fmaf(a.w, b.z, acc2[3][2]);
    acc2[3][3] = fmaf(a.w, b.w, acc2[3][3]);
  }

#pragma unroll
  for (int i = 0; i < 4; ++i) {
    int m = m0 + ty * 4 + i;
    if (m < M) {
      float4 bb = *(const float4*)(base + (size_t)m * HDIM + tx * 4);
      *(float4*)(emb + (size_t)m * HDIM + tx * 4) =
          make_float4(fmaxf(acc2[i][0], 0.f) + bb.x,
                      fmaxf(acc2[i][1], 0.f) + bb.y,
                      fmaxf(acc2[i][2], 0.f) + bb.z,
                      fmaxf(acc2[i][3], 0.f) + bb.w);
    }
  }
}

// ---------------------------------------------------------------------------
// K7: scoring — 4 pairs per wave, 16 lanes (float4 slices) per pair
// ---------------------------------------------------------------------------
__global__ void score_kernel(const int* __restrict__ uidx,
                             const int* __restrict__ bidx,
                             const float* __restrict__ uemb,
                             const float* __restrict__ bemb,
                             const float* __restrict__ ubias,
                             const float* __restrict__ bbias,
                             const float* __restrict__ gbias,
                             float* __restrict__ pred,
                             int batch) {
  int wave = (blockIdx.x * blockDim.x + threadIdx.x) >> 6;
  int lane = threadIdx.x & 63;
  int q = lane & 15, e = lane >> 4;
  int p = wave * 4 + e;            // BATCH_N % 4 == 0
  if (p >= batch) return;
  int u = uidx[p], b = bidx[p];
  float4 uv = ((const float4*)uemb)[(size_t)u * 16 + q];
  float4 bv = ((const float4*)bemb)[(size_t)b * 16 + q];
  float s = uv.x * bv.x + uv.y * bv.y + uv.z * bv.z + uv.w * bv.w;
#pragma unroll
  for (int d = 1; d < 16; d <<= 1) s += __shfl_xor(s, d);
  if (q == 0) {
    float sc = s + ubias[u] + bbias[b] + gbias[0];
    pred[p] = 4.f / (1.f + __expf(-sc)) + 1.f;
  }
}

// ---------------------------------------------------------------------------
extern "C" void kernel_launch(void* const* d_in, const int* in_sizes, int n_in,
                              void* d_out, int out_size, void* d_ws, size_t ws_size,
                              hipStream_t stream) {
  const float* uf    = (const float*)d_in[0];
  const float* bfeat = (const float*)d_in[1];
  const int*   ue    = (const int*)d_in[2];
  const int*   be    = (const int*)d_in[3];
  const int*   bet   = (const int*)d_in[4];
  const int*   uidx  = (const int*)d_in[5];
  const int*   bidx  = (const int*)d_in[6];
  const float* Wu    = (const float*)d_in[7];
  const float* Wb    = (const float*)d_in[8];
  const float* au    = (const float*)d_in[9];
  const float* ab    = (const float*)d_in[10];
  const float* gw    = (const float*)d_in[11];
  const float* Wug   = (const float*)d_in[12];
  const float* bug   = (const float*)d_in[13];
  const float* Wus   = (const float*)d_in[14];
  const float* bus   = (const float*)d_in[15];
  const float* Wbg   = (const float*)d_in[16];
  const float* bbg   = (const float*)d_in[17];
  const float* Wbs   = (const float*)d_in[18];
  const float* bbs   = (const float*)d_in[19];
  const float* Wuo   = (const float*)d_in[20];
  const float* buo   = (const float*)d_in[21];
  const float* Wbo   = (const float*)d_in[22];
  const float* bbo   = (const float*)d_in[23];
  const float* ubase = (const float*)d_in[24];
  const float* bbase = (const float*)d_in[25];
  const float* ubias = (const float*)d_in[26];
  const float* bbias = (const float*)d_in[27];
  const float* gbias = (const float*)d_in[28];

  // Workspace layout (4-byte units)
  float* W4 = (float*)d_ws;
  const size_t NH = (size_t)N_NODES * HDIM;  // 3,200,000
  float* u1     = W4;                        // x1 user; later t_u = uf@Wus
  float* b1     = W4 + NH;                   // x1 business; later t_b
  float* u2     = W4 + 2 * NH;
  float* b2     = W4 + 3 * NH;
  float* ssrc_u = W4 + 4 * NH;
  float* sdst_u = ssrc_u + N_NODES;
  float* ssrc_b = sdst_u + N_NODES;
  float* sdst_b = ssrc_b + N_NODES;
  int*   off_u  = (int*)(sdst_b + N_NODES);  // N+1
  int*   cur_u  = off_u + (N_NODES + 2);
  int*   off_b  = cur_u + N_NODES;           // N+1
  int*   cur_b  = off_b + (N_NODES + 2);
  float2* wdbuf_u = (float2*)(cur_b + N_NODES + 2);  // 8B-aligned (even offset)
  float2* wdbuf_b = wdbuf_u + E_EDGES;

  float* out      = (float*)d_out;
  float* out_pred = out;                     // BATCH_N
  float* out_uemb = out + BATCH_N;           // NH
  float* out_bemb = out + BATCH_N + NH;      // NH

  const int BLK = 256;
  const int tile_blocks = (N_NODES + 63) / 64;              // 782
  const int node_blocks = (N_NODES * 64 + BLK - 1) / BLK;   // wave per node
  const int edge_blocks = (E_EDGES + BLK - 1) / BLK;
  const int pair_blocks = ((BATCH_N / 4) * 64 + BLK - 1) / BLK;  // 4 pairs/wave

  hipMemsetAsync(off_u, 0, (N_NODES + 1) * sizeof(int), stream);
  hipMemsetAsync(off_b, 0, (N_NODES + 1) * sizeof(int), stream);

  // x1 = feat@W + fused attention scalars
  gemm_k256<<<tile_blocks, BLK, 0, stream>>>(uf, Wu, u1, N_NODES, au, ssrc_u, sdst_u);
  gemm_k256<<<tile_blocks, BLK, 0, stream>>>(bfeat, Wb, b1, N_NODES, ab, ssrc_b, sdst_b);

  edge_count<<<edge_blocks, BLK, 0, stream>>>((const int2*)ue, off_u, E_EDGES);
  edge_count<<<edge_blocks, BLK, 0, stream>>>((const int2*)be, off_b, E_EDGES);

  scan_kernel<<<1, 1024, 0, stream>>>(off_u, cur_u, N_NODES);
  scan_kernel<<<1, 1024, 0, stream>>>(off_b, cur_b, N_NODES);

  edge_w_scatter<<<edge_blocks, BLK, 0, stream>>>((const int2*)ue, nullptr, nullptr,
                                                  ssrc_u, sdst_u, cur_u, wdbuf_u, E_EDGES);
  edge_w_scatter<<<edge_blocks, BLK, 0, stream>>>((const int2*)be, bet, gw,
                                                  ssrc_b, sdst_b, cur_b, wdbuf_b, E_EDGES);

  aggregate<<<node_blocks, BLK, 0, stream>>>(off_u, wdbuf_u, u1, u2, N_NODES);
  aggregate<<<node_blocks, BLK, 0, stream>>>(off_b, wdbuf_b, b1, b2, N_NODES);

  // t = feat@Ws, overwriting dead x1 buffers
  gemm_k256<<<tile_blocks, BLK, 0, stream>>>(uf, Wus, u1, N_NODES, nullptr, nullptr, nullptr);
  gemm_k256<<<tile_blocks, BLK, 0, stream>>>(bfeat, Wbs, b1, N_NODES, nullptr, nullptr, nullptr);

  emb_kernel<<<tile_blocks, BLK, 0, stream>>>(u2, u1, Wug, Wuo, bug, bus, buo,
                                              ubase, out_uemb, N_NODES);
  emb_kernel<<<tile_blocks, BLK, 0, stream>>>(b2, b1, Wbg, Wbo, bbg, bbs, bbo,
                                              bbase, out_bemb, N_NODES);

  score_kernel<<<pair_blocks, BLK, 0, stream>>>(uidx, bidx, out_uemb, out_bemb,
                                                ubias, bbias, gbias, out_pred, BATCH_N);
}

// Round 5
// 905.334 us; speedup vs baseline: 2.1509x; 1.1886x over previous
//
#include <hip/hip_runtime.h>
#include <cstdint>
#include <cstddef>

// Problem constants (from reference setup_inputs)
#define N_NODES 50000
#define FDIM    256
#define HDIM    64
#define E_EDGES 1600000
#define BATCH_N 1000000
#define SCAN_BLOCKS 196   // ceil(N_NODES / 256)

// ---------------------------------------------------------------------------
// K1: tiled fp32 GEMM  C[M x 64] = A[M x 256] @ B[256 x 64]
// Optional fused attention scalars: ssrc[m] = C[m,:].a[:64], sdst = C[m,:].a[64:]
// ---------------------------------------------------------------------------
__global__ __launch_bounds__(256) void gemm_k256(const float* __restrict__ A,
                                                 const float* __restrict__ B,
                                                 float* __restrict__ C, int M,
                                                 const float* __restrict__ a_att,
                                                 float* __restrict__ ssrc,
                                                 float* __restrict__ sdst) {
  __shared__ float As[64][68];
  __shared__ float Bs[64][64];
  const int t  = threadIdx.x;
  const int tx = t & 15;        // N direction (cols tx*4..+3)
  const int ty = t >> 4;        // M direction (rows ty*4..+3)
  const int m0 = blockIdx.x * 64;

  float acc[4][4] = {};

  for (int kc = 0; kc < 4; ++kc) {
    __syncthreads();
#pragma unroll
    for (int i = 0; i < 4; ++i) {
      int f = t + i * 256;            // 0..1023
      int row = f >> 4, c4 = f & 15;  // row in tile, float4-col in chunk
      int mg = m0 + row; mg = (mg < M) ? mg : (M - 1);
      float4 va = *(const float4*)(A + (size_t)mg * FDIM + kc * 64 + c4 * 4);
      As[c4 * 4 + 0][row] = va.x;
      As[c4 * 4 + 1][row] = va.y;
      As[c4 * 4 + 2][row] = va.z;
      As[c4 * 4 + 3][row] = va.w;
      *(float4*)(&Bs[row][c4 * 4]) =
          *(const float4*)(B + (size_t)(kc * 64 + row) * HDIM + c4 * 4);
    }
    __syncthreads();
#pragma unroll 4
    for (int k = 0; k < 64; ++k) {
      float4 a = *(const float4*)(&As[k][ty * 4]);
      float4 b = *(const float4*)(&Bs[k][tx * 4]);
      acc[0][0] = fmaf(a.x, b.x, acc[0][0]);
      acc[0][1] = fmaf(a.x, b.y, acc[0][1]);
      acc[0][2] = fmaf(a.x, b.z, acc[0][2]);
      acc[0][3] = fmaf(a.x, b.w, acc[0][3]);
      acc[1][0] = fmaf(a.y, b.x, acc[1][0]);
      acc[1][1] = fmaf(a.y, b.y, acc[1][1]);
      acc[1][2] = fmaf(a.y, b.z, acc[1][2]);
      acc[1][3] = fmaf(a.y, b.w, acc[1][3]);
      acc[2][0] = fmaf(a.z, b.x, acc[2][0]);
      acc[2][1] = fmaf(a.z, b.y, acc[2][1]);
      acc[2][2] = fmaf(a.z, b.z, acc[2][2]);
      acc[2][3] = fmaf(a.z, b.w, acc[2][3]);
      acc[3][0] = fmaf(a.w, b.x, acc[3][0]);
      acc[3][1] = fmaf(a.w, b.y, acc[3][1]);
      acc[3][2] = fmaf(a.w, b.z, acc[3][2]);
      acc[3][3] = fmaf(a.w, b.w, acc[3][3]);
    }
  }

#pragma unroll
  for (int i = 0; i < 4; ++i) {
    int m = m0 + ty * 4 + i;
    if (m < M)
      *(float4*)(C + (size_t)m * HDIM + tx * 4) =
          make_float4(acc[i][0], acc[i][1], acc[i][2], acc[i][3]);
  }

  if (a_att) {
    float4 aa1 = *(const float4*)(a_att + tx * 4);
    float4 aa2 = *(const float4*)(a_att + HDIM + tx * 4);
#pragma unroll
    for (int i = 0; i < 4; ++i) {
      float s1 = acc[i][0] * aa1.x + acc[i][1] * aa1.y +
                 acc[i][2] * aa1.z + acc[i][3] * aa1.w;
      float s2 = acc[i][0] * aa2.x + acc[i][1] * aa2.y +
                 acc[i][2] * aa2.z + acc[i][3] * aa2.w;
#pragma unroll
      for (int d = 1; d < 16; d <<= 1) {
        s1 += __shfl_xor(s1, d);
        s2 += __shfl_xor(s2, d);
      }
      int m = m0 + ty * 4 + i;
      if (tx == 0 && m < M) { ssrc[m] = s1; sdst[m] = s2; }
    }
  }
}

// ---------------------------------------------------------------------------
// K2: per-edge out-degree histogram on src
// ---------------------------------------------------------------------------
__global__ void edge_count(const int2* __restrict__ edges,
                           int* __restrict__ cnt, int n_edges) {
  int e = blockIdx.x * blockDim.x + threadIdx.x;
  if (e >= n_edges) return;
  atomicAdd(&cnt[edges[e].x], 1);
}

// ---------------------------------------------------------------------------
// K3a/b/c: multi-block exclusive scan of the two count arrays.
//   a: per-block LDS scan, counts -> block-local exclusive prefix, psum = sums
//   b: scan the SCAN_BLOCKS partial sums (one block per graph), total -> off[n]
//   c: add block offsets, produce cur copy
// ---------------------------------------------------------------------------
__global__ __launch_bounds__(256) void scan_blk(int* __restrict__ cnt_u,
                                                int* __restrict__ cnt_b,
                                                int* __restrict__ psum) {
  __shared__ int sh[256];
  int* cnt = blockIdx.y ? cnt_b : cnt_u;
  int t = threadIdx.x;
  int i = blockIdx.x * 256 + t;
  int v = (i < N_NODES) ? cnt[i] : 0;
  sh[t] = v;
  __syncthreads();
#pragma unroll
  for (int d = 1; d < 256; d <<= 1) {
    int tv = (t >= d) ? sh[t - d] : 0;
    __syncthreads();
    sh[t] += tv;
    __syncthreads();
  }
  int incl = sh[t];
  if (i < N_NODES) cnt[i] = incl - v;   // exclusive within block
  if (t == 255) psum[blockIdx.y * SCAN_BLOCKS + blockIdx.x] = incl;
}

__global__ __launch_bounds__(256) void scan_top(int* __restrict__ psum,
                                                int* __restrict__ off_u,
                                                int* __restrict__ off_b) {
  __shared__ int sh[256];
  int g = blockIdx.x;
  int t = threadIdx.x;
  int v = (t < SCAN_BLOCKS) ? psum[g * SCAN_BLOCKS + t] : 0;
  sh[t] = v;
  __syncthreads();
#pragma unroll
  for (int d = 1; d < 256; d <<= 1) {
    int tv = (t >= d) ? sh[t - d] : 0;
    __syncthreads();
    sh[t] += tv;
    __syncthreads();
  }
  int incl = sh[t];
  if (t < SCAN_BLOCKS) psum[g * SCAN_BLOCKS + t] = incl - v;  // exclusive
  if (t == SCAN_BLOCKS - 1) {
    int* off = g ? off_b : off_u;
    off[N_NODES] = incl;   // grand total
  }
}

__global__ __launch_bounds__(256) void scan_add(int* __restrict__ off_u,
                                                int* __restrict__ off_b,
                                                int* __restrict__ cur_u,
                                                int* __restrict__ cur_b,
                                                const int* __restrict__ psum) {
  int* off = blockIdx.y ? off_b : off_u;
  int* cur = blockIdx.y ? cur_b : cur_u;
  int i = blockIdx.x * 256 + threadIdx.x;
  if (i < N_NODES) {
    int val = off[i] + psum[blockIdx.y * SCAN_BLOCKS + blockIdx.x];
    off[i] = val;
    cur[i] = val;
  }
}

// ---------------------------------------------------------------------------
// K4: per-edge attention weight + CSR scatter of (w, dst) fused 8B records.
// Scatter store is non-temporal: random 8B stores otherwise cost one partial
// 64B line eviction each (measured 8x WRITE amplification).
// ---------------------------------------------------------------------------
__global__ void edge_w_scatter(const int2* __restrict__ edges,
                               const int* __restrict__ etype,     // nullable
                               const float* __restrict__ gw,      // nullable
                               const float* __restrict__ ssrc,
                               const float* __restrict__ sdst,
                               int* __restrict__ cur,
                               float2* __restrict__ wdbuf,
                               int n_edges) {
  int e = blockIdx.x * blockDim.x + threadIdx.x;
  if (e >= n_edges) return;
  int2 ed = edges[e];
  float x = ssrc[ed.x] + sdst[ed.y];
  x = (x >= 0.f) ? x : 0.2f * x;
  if (etype) x += gw[etype[e]];
  float w = 1.f / (1.f + __expf(-x));
  int pos = atomicAdd(&cur[ed.x], 1);
  union { float2 f2; unsigned long long u; } cvt;
  cvt.f2 = make_float2(w, __int_as_float(ed.y));
  __builtin_nontemporal_store(cvt.u, (unsigned long long*)(wdbuf + pos));
}

// ---------------------------------------------------------------------------
// K5: gather aggregation, one wave per node, 4 edges in flight,
// float4 row slices (16 lanes per row). No float atomics.
// ---------------------------------------------------------------------------
__global__ void aggregate(const int* __restrict__ off,
                          const float2* __restrict__ wdbuf,
                          const float* __restrict__ x1,
                          float* __restrict__ x2,
                          int n_nodes) {
  int wid  = (blockIdx.x * blockDim.x + threadIdx.x) >> 6;
  int lane = threadIdx.x & 63;
  if (wid >= n_nodes) return;
  const int q  = lane & 15;   // float4 slice of the 64-wide row
  const int es = lane >> 4;   // edge slot 0..3
  int beg = off[wid], end = off[wid + 1];
  float4 acc = make_float4(0.f, 0.f, 0.f, 0.f);
  float wsum = 0.f;
  const float4* x1v = (const float4*)x1;
  for (int j = beg; j < end; j += 4) {
    int jj = j + es;
    bool valid = jj < end;
    float2 wd = wdbuf[valid ? jj : beg];   // beg always < end here
    float  w  = valid ? wd.x : 0.f;
    int    d  = __float_as_int(wd.y);
    float4 v  = x1v[(size_t)d * 16 + q];
    acc.x = fmaf(w, v.x, acc.x);
    acc.y = fmaf(w, v.y, acc.y);
    acc.z = fmaf(w, v.z, acc.z);
    acc.w = fmaf(w, v.w, acc.w);
    wsum += w;
  }
#pragma unroll
  for (int d = 16; d < 64; d <<= 1) {
    acc.x += __shfl_xor(acc.x, d);
    acc.y += __shfl_xor(acc.y, d);
    acc.z += __shfl_xor(acc.z, d);
    acc.w += __shfl_xor(acc.w, d);
    wsum  += __shfl_xor(wsum, d);
  }
  if (es == 0) {
    float inv = 1.f / fmaxf(wsum, 1e-8f);
    ((float4*)x2)[(size_t)wid * 16 + q] =
        make_float4(acc.x * inv, acc.y * inv, acc.z * inv, acc.w * inv);
  }
}

// ---------------------------------------------------------------------------
// K6: fused output head (per 64-node tile):
//   u3  = relu(x2@Wg + bg + t + bs)      (t = feat@Ws, precomputed)
//   emb = relu(u3@Wo + bo) + base
// ---------------------------------------------------------------------------
__global__ __launch_bounds__(256) void emb_kernel(const float* __restrict__ x2,
                                                  const float* __restrict__ tadd,
                                                  const float* __restrict__ Wg,
                                                  const float* __restrict__ Wo,
                                                  const float* __restrict__ bg,
                                                  const float* __restrict__ bs,
                                                  const float* __restrict__ bo,
                                                  const float* __restrict__ base,
                                                  float* __restrict__ emb, int M) {
  __shared__ float Xs[64][68];   // x2 transposed [k][m]; reused as u3 [n][m]
  __shared__ float Wgs[64][64];
  __shared__ float Wos[64][64];
  const int t  = threadIdx.x;
  const int tx = t & 15;
  const int ty = t >> 4;
  const int m0 = blockIdx.x * 64;

#pragma unroll
  for (int i = 0; i < 4; ++i) {
    int f = t + i * 256;
    int row = f >> 4, c4 = f & 15;
    int mg = m0 + row; mg = (mg < M) ? mg : (M - 1);
    float4 v = *(const float4*)(x2 + (size_t)mg * HDIM + c4 * 4);
    Xs[c4 * 4 + 0][row] = v.x;
    Xs[c4 * 4 + 1][row] = v.y;
    Xs[c4 * 4 + 2][row] = v.z;
    Xs[c4 * 4 + 3][row] = v.w;
    *(float4*)(&Wgs[row][c4 * 4]) = *(const float4*)(Wg + (size_t)row * HDIM + c4 * 4);
    *(float4*)(&Wos[row][c4 * 4]) = *(const float4*)(Wo + (size_t)row * HDIM + c4 * 4);
  }

  float4 bgv = *(const float4*)(bg + tx * 4);
  float4 bsv = *(const float4*)(bs + tx * 4);
  float acc[4][4];
#pragma unroll
  for (int i = 0; i < 4; ++i) {
    int mg = m0 + ty * 4 + i; mg = (mg < M) ? mg : (M - 1);
    float4 tv = *(const float4*)(tadd + (size_t)mg * HDIM + tx * 4);
    acc[i][0] = tv.x + bgv.x + bsv.x;
    acc[i][1] = tv.y + bgv.y + bsv.y;
    acc[i][2] = tv.z + bgv.z + bsv.z;
    acc[i][3] = tv.w + bgv.w + bsv.w;
  }
  __syncthreads();

#pragma unroll 4
  for (int k = 0; k < 64; ++k) {
    float4 a = *(const float4*)(&Xs[k][ty * 4]);
    float4 b = *(const float4*)(&Wgs[k][tx * 4]);
    acc[0][0] = fmaf(a.x, b.x, acc[0][0]);
    acc[0][1] = fmaf(a.x, b.y, acc[0][1]);
    acc[0][2] = fmaf(a.x, b.z, acc[0][2]);
    acc[0][3] = fmaf(a.x, b.w, acc[0][3]);
    acc[1][0] = fmaf(a.y, b.x, acc[1][0]);
    acc[1][1] = fmaf(a.y, b.y, acc[1][1]);
    acc[1][2] = fmaf(a.y, b.z, acc[1][2]);
    acc[1][3] = fmaf(a.y, b.w, acc[1][3]);
    acc[2][0] = fmaf(a.z, b.x, acc[2][0]);
    acc[2][1] = fmaf(a.z, b.y, acc[2][1]);
    acc[2][2] = fmaf(a.z, b.z, acc[2][2]);
    acc[2][3] = fmaf(a.z, b.w, acc[2][3]);
    acc[3][0] = fmaf(a.w, b.x, acc[3][0]);
    acc[3][1] = fmaf(a.w, b.y, acc[3][1]);
    acc[3][2] = fmaf(a.w, b.z, acc[3][2]);
    acc[3][3] = fmaf(a.w, b.w, acc[3][3]);
  }
  __syncthreads();

#pragma unroll
  for (int i = 0; i < 4; ++i)
#pragma unroll
    for (int j = 0; j < 4; ++j)
      Xs[tx * 4 + j][ty * 4 + i] = fmaxf(acc[i][j], 0.f);
  __syncthreads();

  float4 bov = *(const float4*)(bo + tx * 4);
  float acc2[4][4];
#pragma unroll
  for (int i = 0; i < 4; ++i) {
    acc2[i][0] = bov.x; acc2[i][1] = bov.y; acc2[i][2] = bov.z; acc2[i][3] = bov.w;
  }
#pragma unroll 4
  for (int k = 0; k < 64; ++k) {
    float4 a = *(const float4*)(&Xs[k][ty * 4]);
    float4 b = *(const float4*)(&Wos[k][tx * 4]);
    acc2[0][0] = fmaf(a.x, b.x, acc2[0][0]);
    acc2[0][1] = fmaf(a.x, b.y, acc2[0][1]);
    acc2[0][2] = fmaf(a.x, b.z, acc2[0][2]);
    acc2[0][3] = fmaf(a.x, b.w, acc2[0][3]);
    acc2[1][0] = fmaf(a.y, b.x, acc2[1][0]);
    acc2[1][1] = fmaf(a.y, b.y, acc2[1][1]);
    acc2[1][2] = fmaf(a.y, b.z, acc2[1][2]);
    acc2[1][3] = fmaf(a.y, b.w, acc2[1][3]);
    acc2[2][0] = fmaf(a.z, b.x, acc2[2][0]);
    acc2[2][1] = fmaf(a.z, b.y, acc2[2][1]);
    acc2[2][2] = fmaf(a.z, b.z, acc2[2][2]);
    acc2[2][3] = fmaf(a.z, b.w, acc2[2][3]);
    acc2[3][0] = fmaf(a.w, b.x, acc2[3][0]);
    acc2[3][1] = fmaf(a.w, b.y, acc2[3][1]);
    acc2[3][2] = fmaf(a.w, b.z, acc2[3][2]);
    acc2[3][3] = fmaf(a.w, b.w, acc2[3][3]);
  }

#pragma unroll
  for (int i = 0; i < 4; ++i) {
    int m = m0 + ty * 4 + i;
    if (m < M) {
      float4 bb = *(const float4*)(base + (size_t)m * HDIM + tx * 4);
      *(float4*)(emb + (size_t)m * HDIM + tx * 4) =
          make_float4(fmaxf(acc2[i][0], 0.f) + bb.x,
                      fmaxf(acc2[i][1], 0.f) + bb.y,
                      fmaxf(acc2[i][2], 0.f) + bb.z,
                      fmaxf(acc2[i][3], 0.f) + bb.w);
    }
  }
}

// ---------------------------------------------------------------------------
// K7: scoring — 4 pairs per wave, 16 lanes (float4 slices) per pair
// ---------------------------------------------------------------------------
__global__ void score_kernel(const int* __restrict__ uidx,
                             const int* __restrict__ bidx,
                             const float* __restrict__ uemb,
                             const float* __restrict__ bemb,
                             const float* __restrict__ ubias,
                             const float* __restrict__ bbias,
                             const float* __restrict__ gbias,
                             float* __restrict__ pred,
                             int batch) {
  int wave = (blockIdx.x * blockDim.x + threadIdx.x) >> 6;
  int lane = threadIdx.x & 63;
  int q = lane & 15, e = lane >> 4;
  int p = wave * 4 + e;            // BATCH_N % 4 == 0
  if (p >= batch) return;
  int u = uidx[p], b = bidx[p];
  float4 uv = ((const float4*)uemb)[(size_t)u * 16 + q];
  float4 bv = ((const float4*)bemb)[(size_t)b * 16 + q];
  float s = uv.x * bv.x + uv.y * bv.y + uv.z * bv.z + uv.w * bv.w;
#pragma unroll
  for (int d = 1; d < 16; d <<= 1) s += __shfl_xor(s, d);
  if (q == 0) {
    float sc = s + ubias[u] + bbias[b] + gbias[0];
    pred[p] = 4.f / (1.f + __expf(-sc)) + 1.f;
  }
}

// ---------------------------------------------------------------------------
extern "C" void kernel_launch(void* const* d_in, const int* in_sizes, int n_in,
                              void* d_out, int out_size, void* d_ws, size_t ws_size,
                              hipStream_t stream) {
  const float* uf    = (const float*)d_in[0];
  const float* bfeat = (const float*)d_in[1];
  const int*   ue    = (const int*)d_in[2];
  const int*   be    = (const int*)d_in[3];
  const int*   bet   = (const int*)d_in[4];
  const int*   uidx  = (const int*)d_in[5];
  const int*   bidx  = (const int*)d_in[6];
  const float* Wu    = (const float*)d_in[7];
  const float* Wb    = (const float*)d_in[8];
  const float* au    = (const float*)d_in[9];
  const float* ab    = (const float*)d_in[10];
  const float* gw    = (const float*)d_in[11];
  const float* Wug   = (const float*)d_in[12];
  const float* bug   = (const float*)d_in[13];
  const float* Wus   = (const float*)d_in[14];
  const float* bus   = (const float*)d_in[15];
  const float* Wbg   = (const float*)d_in[16];
  const float* bbg   = (const float*)d_in[17];
  const float* Wbs   = (const float*)d_in[18];
  const float* bbs   = (const float*)d_in[19];
  const float* Wuo   = (const float*)d_in[20];
  const float* buo   = (const float*)d_in[21];
  const float* Wbo   = (const float*)d_in[22];
  const float* bbo   = (const float*)d_in[23];
  const float* ubase = (const float*)d_in[24];
  const float* bbase = (const float*)d_in[25];
  const float* ubias = (const float*)d_in[26];
  const float* bbias = (const float*)d_in[27];
  const float* gbias = (const float*)d_in[28];

  // Workspace layout (4-byte units)
  float* W4 = (float*)d_ws;
  const size_t NH = (size_t)N_NODES * HDIM;  // 3,200,000
  float* u1     = W4;                        // x1 user; later t_u = uf@Wus
  float* b1     = W4 + NH;                   // x1 business; later t_b
  float* u2     = W4 + 2 * NH;
  float* b2     = W4 + 3 * NH;
  float* ssrc_u = W4 + 4 * NH;
  float* sdst_u = ssrc_u + N_NODES;
  float* ssrc_b = sdst_u + N_NODES;
  float* sdst_b = ssrc_b + N_NODES;
  int*   off_u  = (int*)(sdst_b + N_NODES);  // N+1
  int*   cur_u  = off_u + (N_NODES + 2);
  int*   off_b  = cur_u + N_NODES;           // N+1
  int*   cur_b  = off_b + (N_NODES + 2);
  int*   psum   = cur_b + N_NODES;           // 2 * SCAN_BLOCKS
  float2* wdbuf_u = (float2*)(psum + 2 * SCAN_BLOCKS + 2);  // 8B-aligned
  float2* wdbuf_b = wdbuf_u + E_EDGES;

  float* out      = (float*)d_out;
  float* out_pred = out;                     // BATCH_N
  float* out_uemb = out + BATCH_N;           // NH
  float* out_bemb = out + BATCH_N + NH;      // NH

  const int BLK = 256;
  const int tile_blocks = (N_NODES + 63) / 64;              // 782
  const int node_blocks = (N_NODES * 64 + BLK - 1) / BLK;   // wave per node
  const int edge_blocks = (E_EDGES + BLK - 1) / BLK;
  const int pair_blocks = ((BATCH_N / 4) * 64 + BLK - 1) / BLK;  // 4 pairs/wave

  hipMemsetAsync(off_u, 0, (N_NODES + 1) * sizeof(int), stream);
  hipMemsetAsync(off_b, 0, (N_NODES + 1) * sizeof(int), stream);

  // x1 = feat@W + fused attention scalars
  gemm_k256<<<tile_blocks, BLK, 0, stream>>>(uf, Wu, u1, N_NODES, au, ssrc_u, sdst_u);
  gemm_k256<<<tile_blocks, BLK, 0, stream>>>(bfeat, Wb, b1, N_NODES, ab, ssrc_b, sdst_b);

  edge_count<<<edge_blocks, BLK, 0, stream>>>((const int2*)ue, off_u, E_EDGES);
  edge_count<<<edge_blocks, BLK, 0, stream>>>((const int2*)be, off_b, E_EDGES);

  // multi-block exclusive scan (both graphs via grid.y)
  scan_blk<<<dim3(SCAN_BLOCKS, 2), BLK, 0, stream>>>(off_u, off_b, psum);
  scan_top<<<2, BLK, 0, stream>>>(psum, off_u, off_b);
  scan_add<<<dim3(SCAN_BLOCKS, 2), BLK, 0, stream>>>(off_u, off_b, cur_u, cur_b, psum);

  edge_w_scatter<<<edge_blocks, BLK, 0, stream>>>((const int2*)ue, nullptr, nullptr,
                                                  ssrc_u, sdst_u, cur_u, wdbuf_u, E_EDGES);
  edge_w_scatter<<<edge_blocks, BLK, 0, stream>>>((const int2*)be, bet, gw,
                                                  ssrc_b, sdst_b, cur_b, wdbuf_b, E_EDGES);

  aggregate<<<node_blocks, BLK, 0, stream>>>(off_u, wdbuf_u, u1, u2, N_NODES);
  aggregate<<<node_blocks, BLK, 0, stream>>>(off_b, wdbuf_b, b1, b2, N_NODES);

  // t = feat@Ws, overwriting dead x1 buffers
  gemm_k256<<<tile_blocks, BLK, 0, stream>>>(uf, Wus, u1, N_NODES, nullptr, nullptr, nullptr);
  gemm_k256<<<tile_blocks, BLK, 0, stream>>>(bfeat, Wbs, b1, N_NODES, nullptr, nullptr, nullptr);

  emb_kernel<<<tile_blocks, BLK, 0, stream>>>(u2, u1, Wug, Wuo, bug, bus, buo,
                                              ubase, out_uemb, N_NODES);
  emb_kernel<<<tile_blocks, BLK, 0, stream>>>(b2, b1, Wbg, Wbo, bbg, bbs, bbo,
                                              bbase, out_bemb, N_NODES);

  score_kernel<<<pair_blocks, BLK, 0, stream>>>(uidx, bidx, out_uemb, out_bemb,
                                                ubias, bbias, gbias, out_pred, BATCH_N);
}

// Round 6
// 842.575 us; speedup vs baseline: 2.3111x; 1.0745x over previous
//
#include <hip/hip_runtime.h>
#include <cstdint>
#include <cstddef>

// Problem constants (from reference setup_inputs)
#define N_NODES 50000
#define FDIM    256
#define HDIM    64
#define E_EDGES 1600000
#define BATCH_N 1000000
#define NREG    8                       // CSR sub-regions (one per XCD)
#define TOT16   (16 * N_NODES)          // 2 graphs * 8 regions * N counts
#define S0B     ((TOT16 + 1023) / 1024) // 782 level-0 scan blocks

// ---------------------------------------------------------------------------
// K1: tiled fp32 GEMM  C[M x 64] = A[M x 256] @ B[256 x 64]
// Optional fused attention scalars: ssrc[m] = C[m,:].a[:64], sdst = C[m,:].a[64:]
// ---------------------------------------------------------------------------
__global__ __launch_bounds__(256) void gemm_k256(const float* __restrict__ A,
                                                 const float* __restrict__ B,
                                                 float* __restrict__ C, int M,
                                                 const float* __restrict__ a_att,
                                                 float* __restrict__ ssrc,
                                                 float* __restrict__ sdst) {
  __shared__ float As[64][68];
  __shared__ float Bs[64][64];
  const int t  = threadIdx.x;
  const int tx = t & 15;        // N direction (cols tx*4..+3)
  const int ty = t >> 4;        // M direction (rows ty*4..+3)
  const int m0 = blockIdx.x * 64;

  float acc[4][4] = {};

  for (int kc = 0; kc < 4; ++kc) {
    __syncthreads();
#pragma unroll
    for (int i = 0; i < 4; ++i) {
      int f = t + i * 256;            // 0..1023
      int row = f >> 4, c4 = f & 15;  // row in tile, float4-col in chunk
      int mg = m0 + row; mg = (mg < M) ? mg : (M - 1);
      float4 va = *(const float4*)(A + (size_t)mg * FDIM + kc * 64 + c4 * 4);
      As[c4 * 4 + 0][row] = va.x;
      As[c4 * 4 + 1][row] = va.y;
      As[c4 * 4 + 2][row] = va.z;
      As[c4 * 4 + 3][row] = va.w;
      *(float4*)(&Bs[row][c4 * 4]) =
          *(const float4*)(B + (size_t)(kc * 64 + row) * HDIM + c4 * 4);
    }
    __syncthreads();
#pragma unroll 4
    for (int k = 0; k < 64; ++k) {
      float4 a = *(const float4*)(&As[k][ty * 4]);
      float4 b = *(const float4*)(&Bs[k][tx * 4]);
      acc[0][0] = fmaf(a.x, b.x, acc[0][0]);
      acc[0][1] = fmaf(a.x, b.y, acc[0][1]);
      acc[0][2] = fmaf(a.x, b.z, acc[0][2]);
      acc[0][3] = fmaf(a.x, b.w, acc[0][3]);
      acc[1][0] = fmaf(a.y, b.x, acc[1][0]);
      acc[1][1] = fmaf(a.y, b.y, acc[1][1]);
      acc[1][2] = fmaf(a.y, b.z, acc[1][2]);
      acc[1][3] = fmaf(a.y, b.w, acc[1][3]);
      acc[2][0] = fmaf(a.z, b.x, acc[2][0]);
      acc[2][1] = fmaf(a.z, b.y, acc[2][1]);
      acc[2][2] = fmaf(a.z, b.z, acc[2][2]);
      acc[2][3] = fmaf(a.z, b.w, acc[2][3]);
      acc[3][0] = fmaf(a.w, b.x, acc[3][0]);
      acc[3][1] = fmaf(a.w, b.y, acc[3][1]);
      acc[3][2] = fmaf(a.w, b.z, acc[3][2]);
      acc[3][3] = fmaf(a.w, b.w, acc[3][3]);
    }
  }

#pragma unroll
  for (int i = 0; i < 4; ++i) {
    int m = m0 + ty * 4 + i;
    if (m < M)
      *(float4*)(C + (size_t)m * HDIM + tx * 4) =
          make_float4(acc[i][0], acc[i][1], acc[i][2], acc[i][3]);
  }

  if (a_att) {
    float4 aa1 = *(const float4*)(a_att + tx * 4);
    float4 aa2 = *(const float4*)(a_att + HDIM + tx * 4);
#pragma unroll
    for (int i = 0; i < 4; ++i) {
      float s1 = acc[i][0] * aa1.x + acc[i][1] * aa1.y +
                 acc[i][2] * aa1.z + acc[i][3] * aa1.w;
      float s2 = acc[i][0] * aa2.x + acc[i][1] * aa2.y +
                 acc[i][2] * aa2.z + acc[i][3] * aa2.w;
#pragma unroll
      for (int d = 1; d < 16; d <<= 1) {
        s1 += __shfl_xor(s1, d);
        s2 += __shfl_xor(s2, d);
      }
      int m = m0 + ty * 4 + i;
      if (tx == 0 && m < M) { ssrc[m] = s1; sdst[m] = s2; }
    }
  }
}

// ---------------------------------------------------------------------------
// K2: per-edge degree histogram, per-XCD region (g = blockIdx.x & 7).
// Both graphs in one dispatch (grid.y).
// ---------------------------------------------------------------------------
__global__ void edge_count8(const int2* __restrict__ ue,
                            const int2* __restrict__ be,
                            int* __restrict__ cnt8) {
  int e = blockIdx.x * blockDim.x + threadIdx.x;
  if (e >= E_EDGES) return;
  int graph = blockIdx.y;
  int2 ed = graph ? be[e] : ue[e];
  int g = blockIdx.x & (NREG - 1);
  atomicAdd(&cnt8[((graph << 3) + g) * N_NODES + ed.x], 1);
}

// ---------------------------------------------------------------------------
// K3a/b/c: 3-level exclusive scan over the 800k count array (in place).
// ---------------------------------------------------------------------------
__global__ __launch_bounds__(256) void scan0(int* __restrict__ cnt,
                                             int* __restrict__ psum) {
  __shared__ int sh[256];
  int t  = threadIdx.x;
  int i0 = blockIdx.x * 1024 + t * 4;
  int v0 = 0, v1 = 0, v2 = 0, v3 = 0;
  if (i0 + 3 < TOT16) {
    int4 v = *(const int4*)(cnt + i0);
    v0 = v.x; v1 = v.y; v2 = v.z; v3 = v.w;
  } else if (i0 < TOT16) {
    v0 = cnt[i0];
    if (i0 + 1 < TOT16) v1 = cnt[i0 + 1];
    if (i0 + 2 < TOT16) v2 = cnt[i0 + 2];
  }
  int s = v0 + v1 + v2 + v3;
  sh[t] = s;
  __syncthreads();
#pragma unroll
  for (int d = 1; d < 256; d <<= 1) {
    int tv = (t >= d) ? sh[t - d] : 0;
    __syncthreads();
    sh[t] += tv;
    __syncthreads();
  }
  int excl = sh[t] - s;
  if (i0 < TOT16) {
    cnt[i0] = excl;
    if (i0 + 1 < TOT16) cnt[i0 + 1] = excl + v0;
    if (i0 + 2 < TOT16) cnt[i0 + 2] = excl + v0 + v1;
    if (i0 + 3 < TOT16) cnt[i0 + 3] = excl + v0 + v1 + v2;
  }
  if (t == 255) psum[blockIdx.x] = sh[255];
}

__global__ __launch_bounds__(1024) void scan1(int* __restrict__ psum,
                                              int* __restrict__ S) {
  __shared__ int sh[1024];
  int t = threadIdx.x;
  int v = (t < S0B) ? psum[t] : 0;
  sh[t] = v;
  __syncthreads();
#pragma unroll
  for (int d = 1; d < 1024; d <<= 1) {
    int tv = (t >= d) ? sh[t - d] : 0;
    __syncthreads();
    sh[t] += tv;
    __syncthreads();
  }
  if (t < S0B) psum[t] = sh[t] - v;   // exclusive
  if (t == 1023) S[TOT16] = sh[1023]; // grand total (= 2*E_EDGES)
}

__global__ __launch_bounds__(256) void scan2(int* __restrict__ cnt,
                                             int* __restrict__ S,
                                             const int* __restrict__ psum) {
  int i = blockIdx.x * 256 + threadIdx.x;
  if (i < TOT16) {
    int val = cnt[i] + psum[i >> 10];
    S[i]   = val;   // segment starts
    cnt[i] = val;   // reused as bump cursors
  }
}

// ---------------------------------------------------------------------------
// K4: per-edge attention weight + region-partitioned CSR scatter.
// Region g = blockIdx.x & 7 matches edge_count8's mapping, so each 1.6 MB
// region is written by one XCD's blocks -> lines fill in the local L2
// (fix for the measured 8x write amplification). Plain stores on purpose.
// ---------------------------------------------------------------------------
__global__ void edge_w_scatter8(const int2* __restrict__ ue,
                                const int2* __restrict__ be,
                                const int* __restrict__ bet,
                                const float* __restrict__ gw,
                                const float* __restrict__ ssrc_u,
                                const float* __restrict__ sdst_u,
                                const float* __restrict__ ssrc_b,
                                const float* __restrict__ sdst_b,
                                int* __restrict__ cur,
                                float2* __restrict__ wdbuf) {
  int e = blockIdx.x * blockDim.x + threadIdx.x;
  if (e >= E_EDGES) return;
  int graph = blockIdx.y;
  int2 ed = graph ? be[e] : ue[e];
  float x = graph ? (ssrc_b[ed.x] + sdst_b[ed.y])
                  : (ssrc_u[ed.x] + sdst_u[ed.y]);
  x = (x >= 0.f) ? x : 0.2f * x;
  if (graph) x += gw[bet[e]];
  float w = 1.f / (1.f + __expf(-x));
  int g = blockIdx.x & (NREG - 1);
  int pos = atomicAdd(&cur[((graph << 3) + g) * N_NODES + ed.x], 1);
  wdbuf[pos] = make_float2(w, __int_as_float(ed.y));
}

// ---------------------------------------------------------------------------
// K5: gather aggregation over 8 region sub-segments per node.
// One wave per node, 4 records in flight, float4 row slices.
// ---------------------------------------------------------------------------
__global__ void aggregate8(const int* __restrict__ S,
                           const float2* __restrict__ wdbuf,
                           const float* __restrict__ x1u,
                           float* __restrict__ x2u,
                           const float* __restrict__ x1b,
                           float* __restrict__ x2b) {
  int wid  = (blockIdx.x * blockDim.x + threadIdx.x) >> 6;
  int lane = threadIdx.x & 63;
  if (wid >= N_NODES) return;
  const float* x1 = blockIdx.y ? x1b : x1u;
  float*       x2 = blockIdx.y ? x2b : x2u;
  const int*   Sg = S + (blockIdx.y << 3) * N_NODES;
  const int q  = lane & 15;
  const int es = lane >> 4;
  int begv[NREG], endv[NREG];
#pragma unroll
  for (int g = 0; g < NREG; ++g) {
    begv[g] = Sg[g * N_NODES + wid];
    endv[g] = Sg[g * N_NODES + wid + 1];   // scan continuity makes this the end
  }
  float4 acc = make_float4(0.f, 0.f, 0.f, 0.f);
  float wsum = 0.f;
  const float4* x1v = (const float4*)x1;
#pragma unroll
  for (int g = 0; g < NREG; ++g) {
    int beg = begv[g], end = endv[g];
    for (int j = beg; j < end; j += 4) {
      int jj = j + es;
      bool valid = jj < end;
      float2 wd = wdbuf[valid ? jj : beg];
      float  w  = valid ? wd.x : 0.f;
      int    d  = __float_as_int(wd.y);
      float4 v  = x1v[(size_t)d * 16 + q];
      acc.x = fmaf(w, v.x, acc.x);
      acc.y = fmaf(w, v.y, acc.y);
      acc.z = fmaf(w, v.z, acc.z);
      acc.w = fmaf(w, v.w, acc.w);
      wsum += w;
    }
  }
#pragma unroll
  for (int d = 16; d < 64; d <<= 1) {
    acc.x += __shfl_xor(acc.x, d);
    acc.y += __shfl_xor(acc.y, d);
    acc.z += __shfl_xor(acc.z, d);
    acc.w += __shfl_xor(acc.w, d);
    wsum  += __shfl_xor(wsum, d);
  }
  if (es == 0) {
    float inv = 1.f / fmaxf(wsum, 1e-8f);
    ((float4*)x2)[(size_t)wid * 16 + q] =
        make_float4(acc.x * inv, acc.y * inv, acc.z * inv, acc.w * inv);
  }
}

// ---------------------------------------------------------------------------
// K6: fused output head (per 64-node tile):
//   u3  = relu(x2@Wg + bg + t + bs)      (t = feat@Ws, precomputed)
//   emb = relu(u3@Wo + bo) + base
// ---------------------------------------------------------------------------
__global__ __launch_bounds__(256) void emb_kernel(const float* __restrict__ x2,
                                                  const float* __restrict__ tadd,
                                                  const float* __restrict__ Wg,
                                                  const float* __restrict__ Wo,
                                                  const float* __restrict__ bg,
                                                  const float* __restrict__ bs,
                                                  const float* __restrict__ bo,
                                                  const float* __restrict__ base,
                                                  float* __restrict__ emb, int M) {
  __shared__ float Xs[64][68];   // x2 transposed [k][m]; reused as u3 [n][m]
  __shared__ float Wgs[64][64];
  __shared__ float Wos[64][64];
  const int t  = threadIdx.x;
  const int tx = t & 15;
  const int ty = t >> 4;
  const int m0 = blockIdx.x * 64;

#pragma unroll
  for (int i = 0; i < 4; ++i) {
    int f = t + i * 256;
    int row = f >> 4, c4 = f & 15;
    int mg = m0 + row; mg = (mg < M) ? mg : (M - 1);
    float4 v = *(const float4*)(x2 + (size_t)mg * HDIM + c4 * 4);
    Xs[c4 * 4 + 0][row] = v.x;
    Xs[c4 * 4 + 1][row] = v.y;
    Xs[c4 * 4 + 2][row] = v.z;
    Xs[c4 * 4 + 3][row] = v.w;
    *(float4*)(&Wgs[row][c4 * 4]) = *(const float4*)(Wg + (size_t)row * HDIM + c4 * 4);
    *(float4*)(&Wos[row][c4 * 4]) = *(const float4*)(Wo + (size_t)row * HDIM + c4 * 4);
  }

  float4 bgv = *(const float4*)(bg + tx * 4);
  float4 bsv = *(const float4*)(bs + tx * 4);
  float acc[4][4];
#pragma unroll
  for (int i = 0; i < 4; ++i) {
    int mg = m0 + ty * 4 + i; mg = (mg < M) ? mg : (M - 1);
    float4 tv = *(const float4*)(tadd + (size_t)mg * HDIM + tx * 4);
    acc[i][0] = tv.x + bgv.x + bsv.x;
    acc[i][1] = tv.y + bgv.y + bsv.y;
    acc[i][2] = tv.z + bgv.z + bsv.z;
    acc[i][3] = tv.w + bgv.w + bsv.w;
  }
  __syncthreads();

#pragma unroll 4
  for (int k = 0; k < 64; ++k) {
    float4 a = *(const float4*)(&Xs[k][ty * 4]);
    float4 b = *(const float4*)(&Wgs[k][tx * 4]);
    acc[0][0] = fmaf(a.x, b.x, acc[0][0]);
    acc[0][1] = fmaf(a.x, b.y, acc[0][1]);
    acc[0][2] = fmaf(a.x, b.z, acc[0][2]);
    acc[0][3] = fmaf(a.x, b.w, acc[0][3]);
    acc[1][0] = fmaf(a.y, b.x, acc[1][0]);
    acc[1][1] = fmaf(a.y, b.y, acc[1][1]);
    acc[1][2] = fmaf(a.y, b.z, acc[1][2]);
    acc[1][3] = fmaf(a.y, b.w, acc[1][3]);
    acc[2][0] = fmaf(a.z, b.x, acc[2][0]);
    acc[2][1] = fmaf(a.z, b.y, acc[2][1]);
    acc[2][2] = fmaf(a.z, b.z, acc[2][2]);
    acc[2][3] = fmaf(a.z, b.w, acc[2][3]);
    acc[3][0] = fmaf(a.w, b.x, acc[3][0]);
    acc[3][1] = fmaf(a.w, b.y, acc[3][1]);
    acc[3][2] = fmaf(a.w, b.z, acc[3][2]);
    acc[3][3] = fmaf(a.w, b.w, acc[3][3]);
  }
  __syncthreads();

#pragma unroll
  for (int i = 0; i < 4; ++i)
#pragma unroll
    for (int j = 0; j < 4; ++j)
      Xs[tx * 4 + j][ty * 4 + i] = fmaxf(acc[i][j], 0.f);
  __syncthreads();

  float4 bov = *(const float4*)(bo + tx * 4);
  float acc2[4][4];
#pragma unroll
  for (int i = 0; i < 4; ++i) {
    acc2[i][0] = bov.x; acc2[i][1] = bov.y; acc2[i][2] = bov.z; acc2[i][3] = bov.w;
  }
#pragma unroll 4
  for (int k = 0; k < 64; ++k) {
    float4 a = *(const float4*)(&Xs[k][ty * 4]);
    float4 b = *(const float4*)(&Wos[k][tx * 4]);
    acc2[0][0] = fmaf(a.x, b.x, acc2[0][0]);
    acc2[0][1] = fmaf(a.x, b.y, acc2[0][1]);
    acc2[0][2] = fmaf(a.x, b.z, acc2[0][2]);
    acc2[0][3] = fmaf(a.x, b.w, acc2[0][3]);
    acc2[1][0] = fmaf(a.y, b.x, acc2[1][0]);
    acc2[1][1] = fmaf(a.y, b.y, acc2[1][1]);
    acc2[1][2] = fmaf(a.y, b.z, acc2[1][2]);
    acc2[1][3] = fmaf(a.y, b.w, acc2[1][3]);
    acc2[2][0] = fmaf(a.z, b.x, acc2[2][0]);
    acc2[2][1] = fmaf(a.z, b.y, acc2[2][1]);
    acc2[2][2] = fmaf(a.z, b.z, acc2[2][2]);
    acc2[2][3] = fmaf(a.z, b.w, acc2[2][3]);
    acc2[3][0] = fmaf(a.w, b.x, acc2[3][0]);
    acc2[3][1] = fmaf(a.w, b.y, acc2[3][1]);
    acc2[3][2] = fmaf(a.w, b.z, acc2[3][2]);
    acc2[3][3] = fmaf(a.w, b.w, acc2[3][3]);
  }

#pragma unroll
  for (int i = 0; i < 4; ++i) {
    int m = m0 + ty * 4 + i;
    if (m < M) {
      float4 bb = *(const float4*)(base + (size_t)m * HDIM + tx * 4);
      *(float4*)(emb + (size_t)m * HDIM + tx * 4) =
          make_float4(fmaxf(acc2[i][0], 0.f) + bb.x,
                      fmaxf(acc2[i][1], 0.f) + bb.y,
                      fmaxf(acc2[i][2], 0.f) + bb.z,
                      fmaxf(acc2[i][3], 0.f) + bb.w);
    }
  }
}

// ---------------------------------------------------------------------------
// K7: scoring — 4 pairs per wave, 16 lanes (float4 slices) per pair
// ---------------------------------------------------------------------------
__global__ void score_kernel(const int* __restrict__ uidx,
                             const int* __restrict__ bidx,
                             const float* __restrict__ uemb,
                             const float* __restrict__ bemb,
                             const float* __restrict__ ubias,
                             const float* __restrict__ bbias,
                             const float* __restrict__ gbias,
                             float* __restrict__ pred,
                             int batch) {
  int wave = (blockIdx.x * blockDim.x + threadIdx.x) >> 6;
  int lane = threadIdx.x & 63;
  int q = lane & 15, e = lane >> 4;
  int p = wave * 4 + e;            // BATCH_N % 4 == 0
  if (p >= batch) return;
  int u = uidx[p], b = bidx[p];
  float4 uv = ((const float4*)uemb)[(size_t)u * 16 + q];
  float4 bv = ((const float4*)bemb)[(size_t)b * 16 + q];
  float s = uv.x * bv.x + uv.y * bv.y + uv.z * bv.z + uv.w * bv.w;
#pragma unroll
  for (int d = 1; d < 16; d <<= 1) s += __shfl_xor(s, d);
  if (q == 0) {
    float sc = s + ubias[u] + bbias[b] + gbias[0];
    pred[p] = 4.f / (1.f + __expf(-sc)) + 1.f;
  }
}

// ---------------------------------------------------------------------------
extern "C" void kernel_launch(void* const* d_in, const int* in_sizes, int n_in,
                              void* d_out, int out_size, void* d_ws, size_t ws_size,
                              hipStream_t stream) {
  const float* uf    = (const float*)d_in[0];
  const float* bfeat = (const float*)d_in[1];
  const int*   ue    = (const int*)d_in[2];
  const int*   be    = (const int*)d_in[3];
  const int*   bet   = (const int*)d_in[4];
  const int*   uidx  = (const int*)d_in[5];
  const int*   bidx  = (const int*)d_in[6];
  const float* Wu    = (const float*)d_in[7];
  const float* Wb    = (const float*)d_in[8];
  const float* au    = (const float*)d_in[9];
  const float* ab    = (const float*)d_in[10];
  const float* gw    = (const float*)d_in[11];
  const float* Wug   = (const float*)d_in[12];
  const float* bug   = (const float*)d_in[13];
  const float* Wus   = (const float*)d_in[14];
  const float* bus   = (const float*)d_in[15];
  const float* Wbg   = (const float*)d_in[16];
  const float* bbg   = (const float*)d_in[17];
  const float* Wbs   = (const float*)d_in[18];
  const float* bbs   = (const float*)d_in[19];
  const float* Wuo   = (const float*)d_in[20];
  const float* buo   = (const float*)d_in[21];
  const float* Wbo   = (const float*)d_in[22];
  const float* bbo   = (const float*)d_in[23];
  const float* ubase = (const float*)d_in[24];
  const float* bbase = (const float*)d_in[25];
  const float* ubias = (const float*)d_in[26];
  const float* bbias = (const float*)d_in[27];
  const float* gbias = (const float*)d_in[28];

  // Workspace layout (4-byte units)
  float* W4 = (float*)d_ws;
  const size_t NH = (size_t)N_NODES * HDIM;  // 3,200,000
  float* u1     = W4;                        // x1 user; later t_u = uf@Wus
  float* b1     = W4 + NH;                   // x1 business; later t_b
  float* u2     = W4 + 2 * NH;
  float* b2     = W4 + 3 * NH;
  float* ssrc_u = W4 + 4 * NH;
  float* sdst_u = ssrc_u + N_NODES;
  float* ssrc_b = sdst_u + N_NODES;
  float* sdst_b = ssrc_b + N_NODES;
  int*   cnt8   = (int*)(sdst_b + N_NODES);  // TOT16; reused as bump cursors
  int*   S      = cnt8 + TOT16;              // TOT16 + 1 segment starts
  int*   psum   = S + TOT16 + 4;             // S0B partials

  float* out      = (float*)d_out;
  float* out_pred = out;                     // BATCH_N
  float* out_uemb = out + BATCH_N;           // NH
  float* out_bemb = out + BATCH_N + NH;      // NH
  // CSR records live in d_out's emb region: dead before emb_kernel writes it.
  float2* wdbuf = (float2*)(out + BATCH_N);  // 2*E_EDGES float2 = 25.6 MB

  const int BLK = 256;
  const int tile_blocks = (N_NODES + 63) / 64;              // 782
  const int node_blocks = (N_NODES * 64 + BLK - 1) / BLK;   // wave per node
  const int edge_blocks = (E_EDGES + BLK - 1) / BLK;        // 6250
  const int pair_blocks = ((BATCH_N / 4) * 64 + BLK - 1) / BLK;  // 4 pairs/wave

  hipMemsetAsync(cnt8, 0, TOT16 * sizeof(int), stream);

  // x1 = feat@W + fused attention scalars
  gemm_k256<<<tile_blocks, BLK, 0, stream>>>(uf, Wu, u1, N_NODES, au, ssrc_u, sdst_u);
  gemm_k256<<<tile_blocks, BLK, 0, stream>>>(bfeat, Wb, b1, N_NODES, ab, ssrc_b, sdst_b);

  edge_count8<<<dim3(edge_blocks, 2), BLK, 0, stream>>>((const int2*)ue, (const int2*)be, cnt8);

  scan0<<<S0B, BLK, 0, stream>>>(cnt8, psum);
  scan1<<<1, 1024, 0, stream>>>(psum, S);
  scan2<<<TOT16 / BLK, BLK, 0, stream>>>(cnt8, S, psum);

  edge_w_scatter8<<<dim3(edge_blocks, 2), BLK, 0, stream>>>(
      (const int2*)ue, (const int2*)be, bet, gw,
      ssrc_u, sdst_u, ssrc_b, sdst_b, cnt8, wdbuf);

  aggregate8<<<dim3(node_blocks, 2), BLK, 0, stream>>>(S, wdbuf, u1, u2, b1, b2);

  // t = feat@Ws, overwriting dead x1 buffers
  gemm_k256<<<tile_blocks, BLK, 0, stream>>>(uf, Wus, u1, N_NODES, nullptr, nullptr, nullptr);
  gemm_k256<<<tile_blocks, BLK, 0, stream>>>(bfeat, Wbs, b1, N_NODES, nullptr, nullptr, nullptr);

  // emb_kernel overwrites the wdbuf region (wdbuf is dead after aggregate8)
  emb_kernel<<<tile_blocks, BLK, 0, stream>>>(u2, u1, Wug, Wuo, bug, bus, buo,
                                              ubase, out_uemb, N_NODES);
  emb_kernel<<<tile_blocks, BLK, 0, stream>>>(b2, b1, Wbg, Wbo, bbg, bbs, bbo,
                                              bbase, out_bemb, N_NODES);

  score_kernel<<<pair_blocks, BLK, 0, stream>>>(uidx, bidx, out_uemb, out_bemb,
                                                ubias, bbias, gbias, out_pred, BATCH_N);
}